// Round 8
// baseline (434.087 us; speedup 1.0000x reference)
//
#include <hip/hip_runtime.h>
#include <hip/hip_bf16.h>
#include <cstdint>
#include <cstddef>

// ---------------------------------------------------------------------------
// HeteroGNN (2-layer hetero GAT) on MI355X, gfx950.  Round 8.
//  - Gathers repacked: 2 cols/lane (unsigned loads), wave covers 2 rows (C=64)
//    / 4 rows (C=32) per instruction; halves combined via shfl_xor.
//  - WT staging remapped (consecutive threads -> consecutive k) to kill the
//    8-way LDS write conflicts seen in round 7 (1.6M SQ_LDS_BANK_CONFLICT).
//  - CSR bucketing: ABITS 9 / CHUNKE 4096 -> ~392 blocks (was 196) for
//    hist/scatter/deg/place occupancy.
//  - MFMA projections (dual kernels), two-level LDS-bucket CSR, dtype probe,
//    dead-code conv2 b->b skip, softmax max-drop: retained.
// ---------------------------------------------------------------------------

typedef __attribute__((ext_vector_type(8))) short short8;   // 8 bf16 (4 VGPR)
typedef __attribute__((ext_vector_type(4))) float f32x4;    // MFMA acc
typedef unsigned int u32;

#define ABITS 9             // bucket = concat_dst >> ABITS  (512 dsts/bucket)
#define CHUNKE 4096         // edges per block in bucket passes

static __device__ __forceinline__ float b2f(__hip_bfloat16 v) { return __bfloat162float(v); }

static __device__ __forceinline__ float ldf(const void* p, int i, int bf) {
    return bf ? __bfloat162float(((const __hip_bfloat16*)p)[i]) : ((const float*)p)[i];
}

static __device__ __forceinline__ short f2bs(float f) {
    __hip_bfloat16 h = __float2bfloat16(f);
    return *reinterpret_cast<short*>(&h);
}
static __device__ __forceinline__ float bs2f(short s) {
    __hip_bfloat16 h = *reinterpret_cast<__hip_bfloat16*>(&s);
    return __bfloat162float(h);
}
static __device__ __forceinline__ float lo16(u32 u) { return bs2f((short)(u & 0xffffu)); }
static __device__ __forceinline__ float hi16(u32 u) { return bs2f((short)(u >> 16)); }
static __device__ __forceinline__ u32 pack2(float x, float y) {
    return (u32)(unsigned short)f2bs(x) | ((u32)(unsigned short)f2bs(y) << 16);
}
static __device__ __forceinline__ float sel4(const float* a, int i) {
    return i == 0 ? a[0] : i == 1 ? a[1] : i == 2 ? a[2] : a[3];
}
static __device__ __forceinline__ float lrelu2(float x) { return x > 0.f ? x : 0.2f * x; }

// ---- dtype probe ----------------------------------------------------------
__global__ __launch_bounds__(256) void k_detect(const unsigned* __restrict__ w,
                                                int* __restrict__ flag)
{
    __shared__ int s_cnt;
    if (threadIdx.x == 0) s_cnt = 0;
    __syncthreads();
    int c = 0;
#pragma unroll
    for (int j = 0; j < 4; ++j) {
        unsigned u = w[threadIdx.x * 4 + j];
        unsigned e = (u >> 7) & 0xffu;
        c += (e >= 100u && e <= 145u) ? 1 : 0;
    }
    atomicAdd(&s_cnt, c);
    __syncthreads();
    if (threadIdx.x == 0) *flag = (s_cnt > 614) ? 1 : 0;
}

// ---- A1: per-block coarse histogram over buckets (LDS) --------------------
__global__ __launch_bounds__(256) void k_bkt_hist(
    const int* __restrict__ bb_d, const int* __restrict__ pp_d,
    const int* __restrict__ bp_d, int* __restrict__ histM,
    int E_bb, int E_pp, int E_bp, int NB, int NP, int nbkt, int nblk)
{
    __shared__ int h[512];
    for (int i = threadIdx.x; i < nbkt; i += 256) h[i] = 0;
    __syncthreads();
    int E_all = E_bb + E_pp + E_bp;
    int base = blockIdx.x * CHUNKE;
    int end = base + CHUNKE < E_all ? base + CHUNKE : E_all;
    for (int i = base + threadIdx.x; i < end; i += 256) {
        int d;
        if (i < E_bb) d = bb_d[i];
        else if (i < E_bb + E_pp) d = NB + pp_d[i - E_bb];
        else d = NB + NP + bp_d[i - E_bb - E_pp];
        atomicAdd(&h[d >> ABITS], 1);
    }
    __syncthreads();
    for (int i = threadIdx.x; i < nbkt; i += 256)
        histM[(size_t)i * nblk + blockIdx.x] = h[i];
}

// ---- scans ----------------------------------------------------------------
__global__ __launch_bounds__(1024) void k_scan1(const int* __restrict__ deg,
                                                int* __restrict__ out,
                                                int* __restrict__ bsum, int n)
{
    __shared__ int wsum[16];
    int gid = blockIdx.x * 1024 + threadIdx.x;
    int lane = threadIdx.x & 63, wid = threadIdx.x >> 6;
    int v = (gid < n) ? deg[gid] : 0;
    int x = v;
#pragma unroll
    for (int off = 1; off < 64; off <<= 1) {
        int y = __shfl_up(x, off, 64);
        if (lane >= off) x += y;
    }
    if (lane == 63) wsum[wid] = x;
    __syncthreads();
    if (wid == 0 && lane < 16) {
        int w0 = wsum[lane];
#pragma unroll
        for (int off = 1; off < 16; off <<= 1) {
            int y = __shfl_up(w0, off, 16);
            if (lane >= off) w0 += y;
        }
        wsum[lane] = w0;
    }
    __syncthreads();
    int base = (wid > 0) ? wsum[wid - 1] : 0;
    int incl = base + x;
    if (gid < n) out[gid] = incl - v;
    if (threadIdx.x == 1023) bsum[blockIdx.x] = incl;
}

__global__ __launch_bounds__(1024) void k_scan2(int* __restrict__ bsum, int nb)
{
    __shared__ int wsum[16];
    int lane = threadIdx.x & 63, wid = threadIdx.x >> 6;
    int v = (threadIdx.x < nb) ? bsum[threadIdx.x] : 0;
    int x = v;
#pragma unroll
    for (int off = 1; off < 64; off <<= 1) {
        int y = __shfl_up(x, off, 64);
        if (lane >= off) x += y;
    }
    if (lane == 63) wsum[wid] = x;
    __syncthreads();
    if (wid == 0 && lane < 16) {
        int w0 = wsum[lane];
#pragma unroll
        for (int off = 1; off < 16; off <<= 1) {
            int y = __shfl_up(w0, off, 16);
            if (lane >= off) w0 += y;
        }
        wsum[lane] = w0;
    }
    __syncthreads();
    int base = (wid > 0) ? wsum[wid - 1] : 0;
    if (threadIdx.x < nb) bsum[threadIdx.x] = base + x - v;
}

__global__ __launch_bounds__(1024) void k_scan3(int* __restrict__ indptr,
                                                const int* __restrict__ bsum,
                                                int n, int E)
{
    int gid = blockIdx.x * 1024 + threadIdx.x;
    if (gid < n) indptr[gid] += bsum[blockIdx.x];
    if (gid == 0) indptr[n] = E;
}

// ---- A3: bucket scatter via LDS cursors (block-local writes) --------------
__global__ __launch_bounds__(256) void k_bkt_scatter(
    const int* __restrict__ bb_s, const int* __restrict__ bb_d,
    const int* __restrict__ pp_s, const int* __restrict__ pp_d,
    const int* __restrict__ bp_s, const int* __restrict__ bp_d,
    const int* __restrict__ histS, unsigned* __restrict__ ebuf,
    int E_bb, int E_pp, int E_bp, int NB, int NP, int nbkt, int nblk)
{
    __shared__ int cur[512];
    for (int i = threadIdx.x; i < nbkt; i += 256)
        cur[i] = histS[(size_t)i * nblk + blockIdx.x];
    __syncthreads();
    int E_all = E_bb + E_pp + E_bp;
    int base = blockIdx.x * CHUNKE;
    int end = base + CHUNKE < E_all ? base + CHUNKE : E_all;
    for (int i = base + threadIdx.x; i < end; i += 256) {
        int s, d;
        if (i < E_bb) { s = bb_s[i]; d = bb_d[i]; }
        else if (i < E_bb + E_pp) { int j = i - E_bb; s = pp_s[j]; d = NB + pp_d[j]; }
        else { int j = i - E_bb - E_pp; s = bp_s[j]; d = NB + NP + bp_d[j]; }
        int p = atomicAdd(&cur[d >> ABITS], 1);
        ebuf[p] = ((unsigned)(d & ((1 << ABITS) - 1)) << 20) | (unsigned)s;
    }
}

// ---- B1: per-bucket exact degree histogram (LDS) --------------------------
__global__ __launch_bounds__(256) void k_deg(
    const unsigned* __restrict__ ebuf, const int* __restrict__ histS,
    int* __restrict__ deg, int NALL, int E_all, int nbkt, int nblk)
{
    __shared__ int h[1 << ABITS];
    int b = blockIdx.x;
    int d0 = b << ABITS;
    int nloc = NALL - d0 < (1 << ABITS) ? NALL - d0 : (1 << ABITS);
    for (int i = threadIdx.x; i < nloc; i += 256) h[i] = 0;
    __syncthreads();
    int s0 = histS[(size_t)b * nblk];
    int s1 = histS[(size_t)(b + 1) * nblk];
    for (int i = s0 + threadIdx.x; i < s1; i += 256)
        atomicAdd(&h[ebuf[i] >> 20], 1);
    __syncthreads();
    for (int i = threadIdx.x; i < nloc; i += 256) deg[d0 + i] = h[i];
}

// ---- B2: per-bucket placement via LDS cursors -----------------------------
__global__ __launch_bounds__(256) void k_place(
    const unsigned* __restrict__ ebuf, const int* __restrict__ histS,
    const int* __restrict__ ip, int* __restrict__ sidx,
    int NALL, int E_all, int nbkt, int nblk)
{
    __shared__ int cur[1 << ABITS];
    int b = blockIdx.x;
    int d0 = b << ABITS;
    int nloc = NALL - d0 < (1 << ABITS) ? NALL - d0 : (1 << ABITS);
    for (int i = threadIdx.x; i < nloc; i += 256) cur[i] = ip[d0 + i];
    __syncthreads();
    int s0 = histS[(size_t)b * nblk];
    int s1 = histS[(size_t)(b + 1) * nblk];
    for (int i = s0 + threadIdx.x; i < s1; i += 256) {
        unsigned e = ebuf[i];
        int p = atomicAdd(&cur[e >> 20], 1);
        sidx[p] = (int)(e & 0xFFFFFu);
    }
}

// ---- MFMA input projection ------------------------------------------------
template <int CIN>
__global__ __launch_bounds__(256) void k_in_proj_mfma(
    const void* __restrict__ X, const void* __restrict__ W, const void* __restrict__ B,
    __hip_bfloat16* __restrict__ Y, int M, const int* __restrict__ flag)
{
    const int bf = *flag;
    constexpr int KP = 40;
    __shared__ short WT[64 * KP];
    __shared__ float bl[64];
    // conflict-free staging: consecutive threads -> consecutive k
    for (int i = threadIdx.x; i < 64 * CIN; i += 256) {
        int n = i / CIN, k = i - n * CIN;
        WT[n * KP + k] = f2bs(ldf(W, k * 64 + n, bf));
    }
    if (threadIdx.x < 64) bl[threadIdx.x] = ldf(B, threadIdx.x, bf);
    __syncthreads();

    int lane = threadIdx.x & 63;
    int wv   = threadIdx.x >> 6;
    int m = lane & 15, quad = lane >> 4;
    int row0 = (blockIdx.x * 4 + wv) * 16;
    if (row0 >= M) return;

    int arow = row0 + m; if (arow >= M) arow = M - 1;
    short8 a;
#pragma unroll
    for (int j = 0; j < 8; ++j)
        a[j] = f2bs(ldf(X, arow * CIN + quad * 8 + j, bf));

    f32x4 acc[4] = {};
#pragma unroll
    for (int t = 0; t < 4; ++t) {
        short8 b = *(const short8*)&WT[((lane & 15) + 16 * t) * KP + quad * 8];
        acc[t] = __builtin_amdgcn_mfma_f32_16x16x32_bf16(a, b, acc[t], 0, 0, 0);
    }

    if (CIN == 34) {
        float x32[4], x33[4];
#pragma unroll
        for (int r = 0; r < 4; ++r) {
            int row = row0 + quad * 4 + r; if (row >= M) row = M - 1;
            x32[r] = ldf(X, row * CIN + 32, bf);
            x33[r] = ldf(X, row * CIN + 33, bf);
        }
#pragma unroll
        for (int t = 0; t < 4; ++t) {
            int col = (lane & 15) + 16 * t;
            float w32 = bs2f(WT[col * KP + 32]);
            float w33 = bs2f(WT[col * KP + 33]);
#pragma unroll
            for (int r = 0; r < 4; ++r)
                acc[t][r] += x32[r] * w32 + x33[r] * w33;
        }
    }

#pragma unroll
    for (int t = 0; t < 4; ++t) {
        int col = (lane & 15) + 16 * t;
        float bb = bl[col];
#pragma unroll
        for (int r = 0; r < 4; ++r) {
            int row = row0 + quad * 4 + r;
            if (row < M) {
                float v = acc[t][r] + bb;
                v = v > 0.f ? v : 0.01f * v;
                Y[(size_t)row * 64 + col] = __float2bfloat16(v);
            }
        }
    }
}

// ---- MFMA single GAT projection ------------------------------------------
template <int N, bool STORE>
__global__ __launch_bounds__(256) void k_gat_proj_mfma(
    const __hip_bfloat16* __restrict__ H, const void* __restrict__ W,
    const void* __restrict__ a_s, const void* __restrict__ a_d,
    __hip_bfloat16* __restrict__ HS, float* __restrict__ SS, float* __restrict__ SD,
    int M, const int* __restrict__ flag)
{
    const int bf = *flag;
    constexpr int KP = 72;
    constexpr int T = N / 16;
    __shared__ short WT[N * KP];
    for (int i = threadIdx.x; i < N * 64; i += 256) {
        int n = i >> 6, k = i & 63;
        WT[n * KP + k] = f2bs(ldf(W, k * N + n, bf));
    }
    __syncthreads();

    int lane = threadIdx.x & 63;
    int wv   = threadIdx.x >> 6;
    int m = lane & 15, quad = lane >> 4;
    int row0 = (blockIdx.x * 4 + wv) * 16;
    if (row0 >= M) return;

    const short* Hs = (const short*)H;
    int arow = row0 + m; if (arow >= M) arow = M - 1;

    f32x4 acc[T] = {};
#pragma unroll
    for (int ks = 0; ks < 2; ++ks) {
        short8 a = *(const short8*)&Hs[(size_t)arow * 64 + ks * 32 + quad * 8];
#pragma unroll
        for (int t = 0; t < T; ++t) {
            short8 b = *(const short8*)&WT[((lane & 15) + 16 * t) * KP + ks * 32 + quad * 8];
            acc[t] = __builtin_amdgcn_mfma_f32_16x16x32_bf16(a, b, acc[t], 0, 0, 0);
        }
    }

    float asv[T], adv[T];
#pragma unroll
    for (int t = 0; t < T; ++t) {
        int col = (lane & 15) + 16 * t;
        asv[t] = ldf(a_s, col, bf);
        adv[t] = ldf(a_d, col, bf);
    }
    float vs[4] = {}, vd[4] = {};
#pragma unroll
    for (int t = 0; t < T; ++t)
#pragma unroll
        for (int r = 0; r < 4; ++r) {
            vs[r] += acc[t][r] * asv[t];
            vd[r] += acc[t][r] * adv[t];
        }
#pragma unroll
    for (int off = 1; off < 16; off <<= 1)
#pragma unroll
        for (int r = 0; r < 4; ++r) {
            vs[r] += __shfl_xor(vs[r], off);
            vd[r] += __shfl_xor(vd[r], off);
        }
    int c = lane & 15;
    if (c < 8) {
        int row = row0 + quad * 4 + (c & 3);
        if (row < M) {
            if (c < 4) SS[row] = sel4(vs, c & 3);
            else       SD[row] = sel4(vd, c & 3);
        }
    }

    if (STORE) {
#pragma unroll
        for (int t = 0; t < T; ++t) {
            int col = (lane & 15) + 16 * t;
#pragma unroll
            for (int r = 0; r < 4; ++r) {
                int row = row0 + quad * 4 + r;
                if (row < M)
                    HS[(size_t)row * N + col] = __float2bfloat16(acc[t][r]);
            }
        }
    }
}

// ---- MFMA dual GAT projection --------------------------------------------
template <int N1, int N2, bool S1, bool S2>
__global__ __launch_bounds__(256) void k_gat_proj_dual(
    const __hip_bfloat16* __restrict__ H,
    const void* __restrict__ W1, const void* __restrict__ W2,
    const void* __restrict__ as1, const void* __restrict__ ad1,
    const void* __restrict__ as2, const void* __restrict__ ad2,
    __hip_bfloat16* __restrict__ HS1, __hip_bfloat16* __restrict__ HS2,
    float* __restrict__ SS1, float* __restrict__ SD1,
    float* __restrict__ SS2, float* __restrict__ SD2,
    int M, const int* __restrict__ flag)
{
    const int bf = *flag;
    constexpr int KP = 72;
    constexpr int T1 = N1 / 16, T2 = N2 / 16, T = T1 + T2;
    __shared__ short WT[(N1 + N2) * KP];
    for (int i = threadIdx.x; i < N1 * 64; i += 256) {
        int n = i >> 6, k = i & 63;
        WT[n * KP + k] = f2bs(ldf(W1, k * N1 + n, bf));
    }
    for (int i = threadIdx.x; i < N2 * 64; i += 256) {
        int n = i >> 6, k = i & 63;
        WT[(N1 + n) * KP + k] = f2bs(ldf(W2, k * N2 + n, bf));
    }
    __syncthreads();

    int lane = threadIdx.x & 63;
    int wv   = threadIdx.x >> 6;
    int m = lane & 15, quad = lane >> 4;
    int row0 = (blockIdx.x * 4 + wv) * 16;
    if (row0 >= M) return;

    const short* Hs = (const short*)H;
    int arow = row0 + m; if (arow >= M) arow = M - 1;

    f32x4 acc[T] = {};
#pragma unroll
    for (int ks = 0; ks < 2; ++ks) {
        short8 a = *(const short8*)&Hs[(size_t)arow * 64 + ks * 32 + quad * 8];
#pragma unroll
        for (int t = 0; t < T; ++t) {
            short8 b = *(const short8*)&WT[((lane & 15) + 16 * t) * KP + ks * 32 + quad * 8];
            acc[t] = __builtin_amdgcn_mfma_f32_16x16x32_bf16(a, b, acc[t], 0, 0, 0);
        }
    }

    float vs1[4] = {}, vd1[4] = {}, vs2[4] = {}, vd2[4] = {};
#pragma unroll
    for (int t = 0; t < T1; ++t) {
        int col = (lane & 15) + 16 * t;
        float av = ldf(as1, col, bf), dv = ldf(ad1, col, bf);
#pragma unroll
        for (int r = 0; r < 4; ++r) {
            vs1[r] += acc[t][r] * av;
            vd1[r] += acc[t][r] * dv;
        }
    }
#pragma unroll
    for (int t = 0; t < T2; ++t) {
        int col = (lane & 15) + 16 * t;
        float av = ldf(as2, col, bf), dv = ldf(ad2, col, bf);
#pragma unroll
        for (int r = 0; r < 4; ++r) {
            vs2[r] += acc[T1 + t][r] * av;
            vd2[r] += acc[T1 + t][r] * dv;
        }
    }
#pragma unroll
    for (int off = 1; off < 16; off <<= 1)
#pragma unroll
        for (int r = 0; r < 4; ++r) {
            vs1[r] += __shfl_xor(vs1[r], off);
            vd1[r] += __shfl_xor(vd1[r], off);
            vs2[r] += __shfl_xor(vs2[r], off);
            vd2[r] += __shfl_xor(vd2[r], off);
        }
    int c = lane & 15;
    {
        int row = row0 + quad * 4 + (c & 3);
        if (row < M) {
            if (c < 4)       SS1[row] = sel4(vs1, c & 3);
            else if (c < 8)  SD1[row] = sel4(vd1, c & 3);
            else if (c < 12) SS2[row] = sel4(vs2, c & 3);
            else             SD2[row] = sel4(vd2, c & 3);
        }
    }

    if (S1) {
#pragma unroll
        for (int t = 0; t < T1; ++t) {
            int col = (lane & 15) + 16 * t;
#pragma unroll
            for (int r = 0; r < 4; ++r) {
                int row = row0 + quad * 4 + r;
                if (row < M)
                    HS1[(size_t)row * N1 + col] = __float2bfloat16(acc[t][r]);
            }
        }
    }
    if (S2) {
#pragma unroll
        for (int t = 0; t < T2; ++t) {
            int col = (lane & 15) + 16 * t;
#pragma unroll
            for (int r = 0; r < 4; ++r) {
                int row = row0 + quad * 4 + r;
                if (row < M)
                    HS2[(size_t)row * N2 + col] = __float2bfloat16(acc[T1 + t][r]);
            }
        }
    }
}

// ---- gather, one relation w/ self-loop, fused fin (C=64, 2 cols/lane) -----
__global__ __launch_bounds__(256) void k_gather1(
    const int* __restrict__ ip, const int* __restrict__ si,
    const float* __restrict__ SS, const float* __restrict__ SD,
    const __hip_bfloat16* __restrict__ HS, const void* __restrict__ bias,
    __hip_bfloat16* __restrict__ OUT, int M, const int* __restrict__ flag)
{
    const int bf = *flag;
    int lane = threadIdx.x & 63;
    int half = lane >> 5, hl = lane & 31;       // hl = col-pair index
    int d = blockIdx.x * 4 + (threadIdx.x >> 6);
    if (d >= M) return;
    const u32* H32 = (const u32*)HS;            // row stride 32 u32
    float sdd = SD[d];
    float ax = 0.f, ay = 0.f, den = 0.f;
    if (half == 0) {
        float ex = __expf(lrelu2(SS[d] + sdd));
        u32 h = H32[(size_t)d * 32 + hl];
        ax = lo16(h) * ex; ay = hi16(h) * ex; den = ex;
    }
    int j1 = ip[d + 1];
    int j = ip[d] + half;
    for (; j + 2 < j1; j += 4) {
        int s0 = si[j], s1 = si[j + 2];
        u32 h0 = H32[(size_t)s0 * 32 + hl];
        u32 h1 = H32[(size_t)s1 * 32 + hl];
        float e0 = __expf(lrelu2(SS[s0] + sdd));
        float e1 = __expf(lrelu2(SS[s1] + sdd));
        ax += lo16(h0) * e0 + lo16(h1) * e1;
        ay += hi16(h0) * e0 + hi16(h1) * e1;
        den += e0 + e1;
    }
    if (j < j1) {
        int s0 = si[j];
        u32 h0 = H32[(size_t)s0 * 32 + hl];
        float e0 = __expf(lrelu2(SS[s0] + sdd));
        ax += lo16(h0) * e0; ay += hi16(h0) * e0; den += e0;
    }
    ax += __shfl_xor(ax, 32); ay += __shfl_xor(ay, 32); den += __shfl_xor(den, 32);
    if (half == 0) {
        float vx = ax / den + ldf(bias, 2 * hl, bf);
        float vy = ay / den + ldf(bias, 2 * hl + 1, bf);
        vx = vx > 0.f ? vx : 0.01f * vx;
        vy = vy > 0.f ? vy : 0.01f * vy;
        ((u32*)OUT)[(size_t)d * 32 + hl] = pack2(vx, vy);
    }
}

// ---- gather: rel1(self) + rel2(no self), fused fin2 (C=64, 2 cols/lane) ---
__global__ __launch_bounds__(256) void k_gather2(
    const int* __restrict__ ip1, const int* __restrict__ si,
    const float* __restrict__ SS1, const float* __restrict__ SD1,
    const __hip_bfloat16* __restrict__ HS1,
    const int* __restrict__ ip2,
    const float* __restrict__ SS2, const float* __restrict__ SD2,
    const __hip_bfloat16* __restrict__ HS2,
    const void* __restrict__ b1, const void* __restrict__ b2,
    __hip_bfloat16* __restrict__ OUT, int M, const int* __restrict__ flag)
{
    const int bf = *flag;
    int lane = threadIdx.x & 63;
    int half = lane >> 5, hl = lane & 31;
    int d = blockIdx.x * 4 + (threadIdx.x >> 6);
    if (d >= M) return;
    const u32* H1 = (const u32*)HS1;
    const u32* H2 = (const u32*)HS2;
    // relation 1 (self loop)
    float sdd = SD1[d];
    float a1x = 0.f, a1y = 0.f, den1 = 0.f;
    if (half == 0) {
        float ex = __expf(lrelu2(SS1[d] + sdd));
        u32 h = H1[(size_t)d * 32 + hl];
        a1x = lo16(h) * ex; a1y = hi16(h) * ex; den1 = ex;
    }
    int j1 = ip1[d + 1];
    int j = ip1[d] + half;
    for (; j + 2 < j1; j += 4) {
        int s0 = si[j], s1 = si[j + 2];
        u32 h0 = H1[(size_t)s0 * 32 + hl];
        u32 h1 = H1[(size_t)s1 * 32 + hl];
        float e0 = __expf(lrelu2(SS1[s0] + sdd));
        float e1 = __expf(lrelu2(SS1[s1] + sdd));
        a1x += lo16(h0) * e0 + lo16(h1) * e1;
        a1y += hi16(h0) * e0 + hi16(h1) * e1;
        den1 += e0 + e1;
    }
    if (j < j1) {
        int s0 = si[j];
        u32 h0 = H1[(size_t)s0 * 32 + hl];
        float e0 = __expf(lrelu2(SS1[s0] + sdd));
        a1x += lo16(h0) * e0; a1y += hi16(h0) * e0; den1 += e0;
    }
    // relation 2 (no self loop)
    float sdd2 = SD2[d];
    float a2x = 0.f, a2y = 0.f, den2 = 0.f;
    j1 = ip2[d + 1];
    j = ip2[d] + half;
    for (; j + 2 < j1; j += 4) {
        int s0 = si[j], s1 = si[j + 2];
        u32 h0 = H2[(size_t)s0 * 32 + hl];
        u32 h1 = H2[(size_t)s1 * 32 + hl];
        float e0 = __expf(lrelu2(SS2[s0] + sdd2));
        float e1 = __expf(lrelu2(SS2[s1] + sdd2));
        a2x += lo16(h0) * e0 + lo16(h1) * e1;
        a2y += hi16(h0) * e0 + hi16(h1) * e1;
        den2 += e0 + e1;
    }
    if (j < j1) {
        int s0 = si[j];
        u32 h0 = H2[(size_t)s0 * 32 + hl];
        float e0 = __expf(lrelu2(SS2[s0] + sdd2));
        a2x += lo16(h0) * e0; a2y += hi16(h0) * e0; den2 += e0;
    }
    a1x += __shfl_xor(a1x, 32); a1y += __shfl_xor(a1y, 32); den1 += __shfl_xor(den1, 32);
    a2x += __shfl_xor(a2x, 32); a2y += __shfl_xor(a2y, 32); den2 += __shfl_xor(den2, 32);
    if (half == 0) {
        float inv2 = den2 > 0.f ? 1.f / den2 : 0.f;
        float vx = a1x / den1 + a2x * inv2 + ldf(b1, 2 * hl, bf) + ldf(b2, 2 * hl, bf);
        float vy = a1y / den1 + a2y * inv2 + ldf(b1, 2 * hl + 1, bf) + ldf(b2, 2 * hl + 1, bf);
        vx = vx > 0.f ? vx : 0.01f * vx;
        vy = vy > 0.f ? vy : 0.01f * vy;
        ((u32*)OUT)[(size_t)d * 32 + hl] = pack2(vx, vy);
    }
}

// ---- conv2 gather (C=32, 2 cols/lane, 4 rows/wave) + output head ----------
__global__ __launch_bounds__(256) void k_gather_out(
    const int* __restrict__ ip1, const int* __restrict__ si,
    const float* __restrict__ SS1, const float* __restrict__ SD1,
    const __hip_bfloat16* __restrict__ HS1,
    const int* __restrict__ ip2,
    const float* __restrict__ SS2, const float* __restrict__ SD2,
    const __hip_bfloat16* __restrict__ HS2,
    const void* __restrict__ b1, const void* __restrict__ b2,
    const void* __restrict__ Wout, const void* __restrict__ bout,
    void* __restrict__ OUT, int M, const int* __restrict__ flag)
{
    const int bf = *flag;
    int lane = threadIdx.x & 63;
    int q = lane >> 4, hl = lane & 15;          // hl = col-pair (cols 2hl,2hl+1)
    int d = blockIdx.x * 4 + (threadIdx.x >> 6);
    if (d >= M) return;
    const u32* H1 = (const u32*)HS1;            // row stride 16 u32
    const u32* H2 = (const u32*)HS2;
    float sdd = SD1[d];
    float a1x = 0.f, a1y = 0.f, den1 = 0.f;
    if (q == 0) {
        float ex = __expf(lrelu2(SS1[d] + sdd));
        u32 h = H1[(size_t)d * 16 + hl];
        a1x = lo16(h) * ex; a1y = hi16(h) * ex; den1 = ex;
    }
    int j1 = ip1[d + 1];
    for (int j = ip1[d] + q; j < j1; j += 4) {
        int s0 = si[j];
        u32 h0 = H1[(size_t)s0 * 16 + hl];
        float e0 = __expf(lrelu2(SS1[s0] + sdd));
        a1x += lo16(h0) * e0; a1y += hi16(h0) * e0; den1 += e0;
    }
    float sdd2 = SD2[d];
    float a2x = 0.f, a2y = 0.f, den2 = 0.f;
    j1 = ip2[d + 1];
    for (int j = ip2[d] + q; j < j1; j += 4) {
        int s0 = si[j];
        u32 h0 = H2[(size_t)s0 * 16 + hl];
        float e0 = __expf(lrelu2(SS2[s0] + sdd2));
        a2x += lo16(h0) * e0; a2y += hi16(h0) * e0; den2 += e0;
    }
    a1x += __shfl_xor(a1x, 16); a1y += __shfl_xor(a1y, 16); den1 += __shfl_xor(den1, 16);
    a2x += __shfl_xor(a2x, 16); a2y += __shfl_xor(a2y, 16); den2 += __shfl_xor(den2, 16);
    a1x += __shfl_xor(a1x, 32); a1y += __shfl_xor(a1y, 32); den1 += __shfl_xor(den1, 32);
    a2x += __shfl_xor(a2x, 32); a2y += __shfl_xor(a2y, 32); den2 += __shfl_xor(den2, 32);
    float inv2 = den2 > 0.f ? 1.f / den2 : 0.f;
    float vx = a1x / den1 + a2x * inv2 + ldf(b1, 2 * hl, bf) + ldf(b2, 2 * hl, bf);
    float vy = a1y / den1 + a2y * inv2 + ldf(b1, 2 * hl + 1, bf) + ldf(b2, 2 * hl + 1, bf);
    vx = vx > 0.f ? vx : 0.01f * vx;
    vy = vy > 0.f ? vy : 0.01f * vy;
    float t = vx * ldf(Wout, 2 * hl, bf) + vy * ldf(Wout, 2 * hl + 1, bf);
#pragma unroll
    for (int off = 1; off < 16; off <<= 1) t += __shfl_xor(t, off);
    if (lane == 0) {
        float r = t + ldf(bout, 0, bf);
        if (bf) ((__hip_bfloat16*)OUT)[d] = __float2bfloat16(r);
        else    ((float*)OUT)[d] = r;
    }
}

// ---------------------------------------------------------------------------
extern "C" void kernel_launch(void* const* d_in, const int* in_sizes, int n_in,
                              void* d_out, int out_size, void* d_ws, size_t ws_size,
                              hipStream_t stream)
{
    const void* x_b = d_in[0];
    const void* x_p = d_in[1];
    const int* ei_bb = (const int*)d_in[2];
    const int* ei_pp = (const int*)d_in[3];
    const int* bp_s  = (const int*)d_in[4];
    const int* bp_d  = (const int*)d_in[5];
    const void *W_in_b = d_in[6],  *b_in_b = d_in[7];
    const void *W_in_p = d_in[8],  *b_in_p = d_in[9];
    const void *W_bb1 = d_in[10], *as_bb1 = d_in[11], *ad_bb1 = d_in[12], *b_bb1 = d_in[13];
    const void *W_pp1 = d_in[14], *as_pp1 = d_in[15], *ad_pp1 = d_in[16], *b_pp1 = d_in[17];
    const void *Ws_bp1 = d_in[18], *Wd_bp1 = d_in[19], *as_bp1 = d_in[20], *ad_bp1 = d_in[21], *b_bp1 = d_in[22];
    // d_in[23..26] = conv2 b->b params: dead code in reference
    const void *W_pp2 = d_in[27], *as_pp2 = d_in[28], *ad_pp2 = d_in[29], *b_pp2 = d_in[30];
    const void *Ws_bp2 = d_in[31], *Wd_bp2 = d_in[32], *as_bp2 = d_in[33], *ad_bp2 = d_in[34], *b_bp2 = d_in[35];
    const void *W_out = d_in[36], *b_out = d_in[37];

    const int NB   = in_sizes[0] / 32;
    const int NP   = in_sizes[1] / 34;
    const int E_bb = in_sizes[2] / 2;
    const int E_pp = in_sizes[3] / 2;
    const int E_bp = in_sizes[4];
    const int E_all = E_bb + E_pp + E_bp;
    const int NALL  = NB + 2 * NP;
    const int* bb_s = ei_bb;  const int* bb_d = ei_bb + E_bb;
    const int* pp_s = ei_pp;  const int* pp_d = ei_pp + E_pp;
    (void)ws_size; (void)n_in; (void)out_size;

    const int nbkt  = (NALL + (1 << ABITS) - 1) >> ABITS;
    const int nblk  = (E_all + CHUNKE - 1) / CHUNKE;
    const int nh    = nbkt * nblk;

    typedef __hip_bfloat16 bf16;
    char* base = (char*)d_ws;
    size_t o = 0;
    auto alloc = [&](size_t bytes) { char* p = base + o; o += (bytes + 255) & ~(size_t)255; return p; };

    // --- small persistent ---
    int* flag  = (int*)alloc(256);
    int* bsum  = (int*)alloc(1024 * 4);
    int* histM = (int*)alloc((size_t)nh * 4);
    int* histS = (int*)alloc((size_t)(nh + 1) * 4);
    int* degA  = (int*)alloc((size_t)NALL * 4);
    int* ip_all = (int*)alloc((size_t)(NALL + 1) * 4);
    unsigned* ebuf = (unsigned*)alloc((size_t)E_all * 4);
    int* si_all = (int*)alloc((size_t)E_all * 4);
    float* ss_bb = (float*)alloc((size_t)NB * 4);
    float* sd_bb = (float*)alloc((size_t)NB * 4);
    float* ss_bp = (float*)alloc((size_t)NB * 4);
    float* ss_pp = (float*)alloc((size_t)NP * 4);
    float* sd_pp = (float*)alloc((size_t)NP * 4);
    float* sd_bp = (float*)alloc((size_t)NP * 4);
    float* ss2_bp = ss_bb;   // ss_bb dead after gather bb
    float* ss2_pp = ss_pp;   // conv1 p-scores dead after gather2
    float* sd2_pp = sd_pp;
    float* sd2_bp = sd_bp;
    float* junkNB = (float*)degA;            // degA dead after scan
    float* junkNP = (float*)(degA + NB);

    // --- feature slots (liveness hand-verified, rounds 4-7) ---
    char* S1 = alloc((size_t)NB * 64 * 2);   // hb -> hs2_bp (NB*32)
    char* S2 = alloc((size_t)NP * 64 * 2);   // hp -> hs2_pp (NP*32)
    char* S3 = alloc((size_t)NB * 64 * 2);   // hs_bb -> hp2 (NP*64)
    char* S4 = alloc((size_t)NB * 64 * 2);   // hb2
    char* S5 = alloc((size_t)NB * 64 * 2);   // hs_bp
    char* S6 = alloc((size_t)NP * 64 * 2);   // hs_pp

    bf16* hb     = (bf16*)S1;
    bf16* hp     = (bf16*)S2;
    bf16* hs_bb  = (bf16*)S3;
    bf16* hb2    = (bf16*)S4;
    bf16* hs_bp  = (bf16*)S5;
    bf16* hs_pp  = (bf16*)S6;
    bf16* hp2    = (bf16*)S3;
    bf16* hs2_pp = (bf16*)S2;
    bf16* hs2_bp = (bf16*)S1;

    auto cdiv = [](int a, int b) { return (a + b - 1) / b; };

    // 0. dtype probe
    k_detect<<<1, 256, 0, stream>>>((const unsigned*)x_b, flag);

    // 1. CSR build, two-level LDS bucketing (no global atomics)
    k_bkt_hist<<<nblk, 256, 0, stream>>>(bb_d, pp_d, bp_d, histM,
                                         E_bb, E_pp, E_bp, NB, NP, nbkt, nblk);
    int sb1 = cdiv(nh, 1024);
    k_scan1<<<sb1, 1024, 0, stream>>>(histM, histS, bsum, nh);
    k_scan2<<<1, 1024, 0, stream>>>(bsum, sb1);
    k_scan3<<<sb1, 1024, 0, stream>>>(histS, bsum, nh, E_all);
    k_bkt_scatter<<<nblk, 256, 0, stream>>>(bb_s, bb_d, pp_s, pp_d, bp_s, bp_d,
                                            histS, ebuf, E_bb, E_pp, E_bp, NB, NP, nbkt, nblk);
    k_deg<<<nbkt, 256, 0, stream>>>(ebuf, histS, degA, NALL, E_all, nbkt, nblk);
    int sb2 = cdiv(NALL, 1024);
    k_scan1<<<sb2, 1024, 0, stream>>>(degA, ip_all, bsum, NALL);
    k_scan2<<<1, 1024, 0, stream>>>(bsum, sb2);
    k_scan3<<<sb2, 1024, 0, stream>>>(ip_all, bsum, NALL, E_all);
    k_place<<<nbkt, 256, 0, stream>>>(ebuf, histS, ip_all, si_all, NALL, E_all, nbkt, nblk);

    const int* ip_bb = ip_all;
    const int* ip_pp = ip_all + NB;
    const int* ip_bp = ip_all + NB + NP;

    // 2. input projections (MFMA)
    k_in_proj_mfma<32><<<cdiv(NB, 64), 256, 0, stream>>>(x_b, W_in_b, b_in_b, hb, NB, flag);
    k_in_proj_mfma<34><<<cdiv(NP, 64), 256, 0, stream>>>(x_p, W_in_p, b_in_p, hp, NP, flag);

    // 3. conv1 projections: dual kernels (shared input), then gathers
    k_gat_proj_dual<64, 64, true, true><<<cdiv(NB, 64), 256, 0, stream>>>(
        hb, W_bb1, Ws_bp1, as_bb1, ad_bb1, as_bp1, ad_bp1,
        hs_bb, hs_bp, ss_bb, sd_bb, ss_bp, junkNB, NB, flag);
    k_gather1<<<cdiv(NB, 4), 256, 0, stream>>>(ip_bb, si_all, ss_bb, sd_bb, hs_bb, b_bb1, hb2, NB, flag);

    k_gat_proj_dual<64, 64, true, false><<<cdiv(NP, 64), 256, 0, stream>>>(
        hp, W_pp1, Wd_bp1, as_pp1, ad_pp1, as_bp1, ad_bp1,
        hs_pp, nullptr, ss_pp, sd_pp, junkNP, sd_bp, NP, flag);
    k_gather2<<<cdiv(NP, 4), 256, 0, stream>>>(ip_pp, si_all, ss_pp, sd_pp, hs_pp,
                                               ip_bp, ss_bp, sd_bp, hs_bp,
                                               b_pp1, b_bp1, hp2, NP, flag);

    // 4. conv2 projections: hp2 dual (pp2 + bp2-dst), hb2 single (bp2-src)
    k_gat_proj_dual<32, 32, true, false><<<cdiv(NP, 64), 256, 0, stream>>>(
        hp2, W_pp2, Wd_bp2, as_pp2, ad_pp2, as_bp2, ad_bp2,
        hs2_pp, nullptr, ss2_pp, sd2_pp, junkNP, sd2_bp, NP, flag);
    k_gat_proj_mfma<32, true><<<cdiv(NB, 64), 256, 0, stream>>>(
        hb2, Ws_bp2, as_bp2, ad_bp2, hs2_bp, ss2_bp, junkNB, NB, flag);

    // 5. conv2 gather + output head fused
    k_gather_out<<<cdiv(NP, 4), 256, 0, stream>>>(ip_pp, si_all, ss2_pp, sd2_pp, hs2_pp,
                                                  ip_bp, ss2_bp, sd2_bp, hs2_bp,
                                                  b_pp2, b_bp2, W_out, b_out, d_out, NP, flag);
}

// Round 9
// 407.914 us; speedup vs baseline: 1.0642x; 1.0642x over previous
//
#include <hip/hip_runtime.h>
#include <hip/hip_bf16.h>
#include <cstdint>
#include <cstddef>

// ---------------------------------------------------------------------------
// HeteroGNN (2-layer hetero GAT) on MI355X, gfx950.  Round 9: fusion round.
//  - CSR finalize: deg + in-bucket scan + place fused into ONE per-bucket
//    kernel (ebuf is bucket-sorted, so each bucket's CSR window is
//    [histS[b], histS[b+1]) and the per-dst scan is bucket-local in LDS).
//  - Grid-split merges (block-uniform branches): dtype probe inside
//    k_bkt_hist block 0; both input projections in one kernel; both conv1
//    dual projections in one kernel; gather1+gather2 in ONE dispatch
//    (latencies overlap); conv2 dual32+single32 in one kernel.
//  - Dispatches: 19 -> 11.
//  - MFMA projections, two-level LDS-bucket CSR, softmax max-drop, dead-code
//    conv2 b->b skip: retained from rounds 5-8.
// ---------------------------------------------------------------------------

typedef __attribute__((ext_vector_type(8))) short short8;   // 8 bf16 (4 VGPR)
typedef __attribute__((ext_vector_type(4))) float f32x4;    // MFMA acc
typedef unsigned int u32;
typedef __hip_bfloat16 bf16;

#define ABITS 9             // bucket = concat_dst >> ABITS  (512 dsts/bucket)
#define CHUNKE 4096         // edges per block in bucket passes

static __device__ __forceinline__ float b2f(bf16 v) { return __bfloat162float(v); }

static __device__ __forceinline__ float ldf(const void* p, int i, int bf) {
    return bf ? __bfloat162float(((const bf16*)p)[i]) : ((const float*)p)[i];
}

static __device__ __forceinline__ short f2bs(float f) {
    bf16 h = __float2bfloat16(f);
    return *reinterpret_cast<short*>(&h);
}
static __device__ __forceinline__ float bs2f(short s) {
    bf16 h = *reinterpret_cast<bf16*>(&s);
    return __bfloat162float(h);
}
static __device__ __forceinline__ float lo16(u32 u) { return bs2f((short)(u & 0xffffu)); }
static __device__ __forceinline__ float hi16(u32 u) { return bs2f((short)(u >> 16)); }
static __device__ __forceinline__ u32 pack2(float x, float y) {
    return (u32)(unsigned short)f2bs(x) | ((u32)(unsigned short)f2bs(y) << 16);
}
static __device__ __forceinline__ float sel4(const float* a, int i) {
    return i == 0 ? a[0] : i == 1 ? a[1] : i == 2 ? a[2] : a[3];
}
static __device__ __forceinline__ float lrelu2(float x) { return x > 0.f ? x : 0.2f * x; }

// ---- A1: per-block coarse bucket histogram (block 0 also runs dtype probe) -
__global__ __launch_bounds__(256) void k_bkt_hist(
    const int* __restrict__ bb_d, const int* __restrict__ pp_d,
    const int* __restrict__ bp_d, int* __restrict__ histM,
    const unsigned* __restrict__ probe_w, int* __restrict__ flag,
    int E_bb, int E_pp, int E_bp, int NB, int NP, int nbkt, int nblk)
{
    if (blockIdx.x == 0) {      // dtype probe (block-uniform branch)
        __shared__ int s_cnt;
        if (threadIdx.x == 0) s_cnt = 0;
        __syncthreads();
        int c = 0;
#pragma unroll
        for (int j = 0; j < 4; ++j) {
            unsigned u = probe_w[threadIdx.x * 4 + j];
            unsigned e = (u >> 7) & 0xffu;
            c += (e >= 100u && e <= 145u) ? 1 : 0;
        }
        atomicAdd(&s_cnt, c);
        __syncthreads();
        if (threadIdx.x == 0) *flag = (s_cnt > 614) ? 1 : 0;
    }
    __shared__ int h[1 << ABITS];
    for (int i = threadIdx.x; i < nbkt; i += 256) h[i] = 0;
    __syncthreads();
    int E_all = E_bb + E_pp + E_bp;
    int base = blockIdx.x * CHUNKE;
    int end = base + CHUNKE < E_all ? base + CHUNKE : E_all;
    for (int i = base + threadIdx.x; i < end; i += 256) {
        int d;
        if (i < E_bb) d = bb_d[i];
        else if (i < E_bb + E_pp) d = NB + pp_d[i - E_bb];
        else d = NB + NP + bp_d[i - E_bb - E_pp];
        atomicAdd(&h[d >> ABITS], 1);
    }
    __syncthreads();
    for (int i = threadIdx.x; i < nbkt; i += 256)
        histM[(size_t)i * nblk + blockIdx.x] = h[i];
}

// ---- scans over histM -----------------------------------------------------
__global__ __launch_bounds__(1024) void k_scan1(const int* __restrict__ deg,
                                                int* __restrict__ out,
                                                int* __restrict__ bsum, int n)
{
    __shared__ int wsum[16];
    int gid = blockIdx.x * 1024 + threadIdx.x;
    int lane = threadIdx.x & 63, wid = threadIdx.x >> 6;
    int v = (gid < n) ? deg[gid] : 0;
    int x = v;
#pragma unroll
    for (int off = 1; off < 64; off <<= 1) {
        int y = __shfl_up(x, off, 64);
        if (lane >= off) x += y;
    }
    if (lane == 63) wsum[wid] = x;
    __syncthreads();
    if (wid == 0 && lane < 16) {
        int w0 = wsum[lane];
#pragma unroll
        for (int off = 1; off < 16; off <<= 1) {
            int y = __shfl_up(w0, off, 16);
            if (lane >= off) w0 += y;
        }
        wsum[lane] = w0;
    }
    __syncthreads();
    int base = (wid > 0) ? wsum[wid - 1] : 0;
    int incl = base + x;
    if (gid < n) out[gid] = incl - v;
    if (threadIdx.x == 1023) bsum[blockIdx.x] = incl;
}

__global__ __launch_bounds__(1024) void k_scan2(int* __restrict__ bsum, int nb)
{
    __shared__ int wsum[16];
    int lane = threadIdx.x & 63, wid = threadIdx.x >> 6;
    int v = (threadIdx.x < nb) ? bsum[threadIdx.x] : 0;
    int x = v;
#pragma unroll
    for (int off = 1; off < 64; off <<= 1) {
        int y = __shfl_up(x, off, 64);
        if (lane >= off) x += y;
    }
    if (lane == 63) wsum[wid] = x;
    __syncthreads();
    if (wid == 0 && lane < 16) {
        int w0 = wsum[lane];
#pragma unroll
        for (int off = 1; off < 16; off <<= 1) {
            int y = __shfl_up(w0, off, 16);
            if (lane >= off) w0 += y;
        }
        wsum[lane] = w0;
    }
    __syncthreads();
    int base = (wid > 0) ? wsum[wid - 1] : 0;
    if (threadIdx.x < nb) bsum[threadIdx.x] = base + x - v;
}

__global__ __launch_bounds__(1024) void k_scan3(int* __restrict__ indptr,
                                                const int* __restrict__ bsum,
                                                int n, int E)
{
    int gid = blockIdx.x * 1024 + threadIdx.x;
    if (gid < n) indptr[gid] += bsum[blockIdx.x];
    if (gid == 0) indptr[n] = E;
}

// ---- A3: bucket scatter via LDS cursors -----------------------------------
__global__ __launch_bounds__(256) void k_bkt_scatter(
    const int* __restrict__ bb_s, const int* __restrict__ bb_d,
    const int* __restrict__ pp_s, const int* __restrict__ pp_d,
    const int* __restrict__ bp_s, const int* __restrict__ bp_d,
    const int* __restrict__ histS, unsigned* __restrict__ ebuf,
    int E_bb, int E_pp, int E_bp, int NB, int NP, int nbkt, int nblk)
{
    __shared__ int cur[1 << ABITS];
    for (int i = threadIdx.x; i < nbkt; i += 256)
        cur[i] = histS[(size_t)i * nblk + blockIdx.x];
    __syncthreads();
    int E_all = E_bb + E_pp + E_bp;
    int base = blockIdx.x * CHUNKE;
    int end = base + CHUNKE < E_all ? base + CHUNKE : E_all;
    for (int i = base + threadIdx.x; i < end; i += 256) {
        int s, d;
        if (i < E_bb) { s = bb_s[i]; d = bb_d[i]; }
        else if (i < E_bb + E_pp) { int j = i - E_bb; s = pp_s[j]; d = NB + pp_d[j]; }
        else { int j = i - E_bb - E_pp; s = bp_s[j]; d = NB + NP + bp_d[j]; }
        int p = atomicAdd(&cur[d >> ABITS], 1);
        ebuf[p] = ((unsigned)(d & ((1 << ABITS) - 1)) << 20) | (unsigned)s;
    }
}

// ---- fused finalize: per-bucket degree hist + LDS scan + ip write + place -
__global__ __launch_bounds__(256) void k_finalize(
    const unsigned* __restrict__ ebuf, const int* __restrict__ histS,
    int* __restrict__ ip_all, int* __restrict__ sidx,
    int NALL, int E_all, int nbkt, int nblk)
{
    __shared__ int h[1 << ABITS];
    __shared__ int pre[1 << ABITS];
    __shared__ int wq[4];
    int b = blockIdx.x;
    int d0 = b << ABITS;
    int nloc = NALL - d0 < (1 << ABITS) ? NALL - d0 : (1 << ABITS);
    int t = threadIdx.x;
    for (int i = t; i < (1 << ABITS); i += 256) h[i] = 0;
    __syncthreads();
    int s0 = histS[(size_t)b * nblk];
    int s1 = histS[(size_t)(b + 1) * nblk];   // histS[nh] == E_all
    // pass 1: exact per-dst degree histogram
    for (int i = s0 + t; i < s1; i += 256)
        atomicAdd(&h[ebuf[i] >> 20], 1);
    __syncthreads();
    // exclusive scan of h[0..512) -> pre (2 elems/thread + 256-wide scan)
    int v0 = h[2 * t], v1 = h[2 * t + 1];
    int ps = v0 + v1;
    int lane = t & 63, wid = t >> 6;
    int x = ps;
#pragma unroll
    for (int off = 1; off < 64; off <<= 1) {
        int y = __shfl_up(x, off, 64);
        if (lane >= off) x += y;
    }
    if (lane == 63) wq[wid] = x;
    __syncthreads();
    if (t == 0) {
        int a = 0;
#pragma unroll
        for (int w = 0; w < 4; ++w) { int tmp = wq[w]; wq[w] = a; a += tmp; }
    }
    __syncthreads();
    int excl = wq[wid] + x - ps;
    pre[2 * t]     = excl;
    pre[2 * t + 1] = excl + v0;
    __syncthreads();
    // write ip window (coalesced) and seed cursors
    for (int i = t; i < nloc; i += 256) ip_all[d0 + i] = s0 + pre[i];
    if (d0 + nloc == NALL && t == 0) ip_all[NALL] = E_all;
    for (int i = t; i < (1 << ABITS); i += 256) h[i] = s0 + pre[i];
    __syncthreads();
    // pass 2: place
    for (int i = s0 + t; i < s1; i += 256) {
        unsigned e = ebuf[i];
        int p = atomicAdd(&h[e >> 20], 1);
        sidx[p] = (int)(e & 0xFFFFFu);
    }
}

// ---- MFMA input projection body -------------------------------------------
template <int CIN>
static __device__ __forceinline__ void in_proj_body(
    short* WT, float* bl, int bid,
    const void* __restrict__ X, const void* __restrict__ W, const void* __restrict__ B,
    bf16* __restrict__ Y, int M, int bf)
{
    constexpr int KP = 40;
    for (int i = threadIdx.x; i < 64 * CIN; i += 256) {
        int n = i / CIN, k = i - n * CIN;
        WT[n * KP + k] = f2bs(ldf(W, k * 64 + n, bf));
    }
    if (threadIdx.x < 64) bl[threadIdx.x] = ldf(B, threadIdx.x, bf);
    __syncthreads();

    int lane = threadIdx.x & 63;
    int wv   = threadIdx.x >> 6;
    int m = lane & 15, quad = lane >> 4;
    int row0 = (bid * 4 + wv) * 16;
    if (row0 >= M) return;

    int arow = row0 + m; if (arow >= M) arow = M - 1;
    short8 a;
#pragma unroll
    for (int j = 0; j < 8; ++j)
        a[j] = f2bs(ldf(X, arow * CIN + quad * 8 + j, bf));

    f32x4 acc[4] = {};
#pragma unroll
    for (int tt = 0; tt < 4; ++tt) {
        short8 bfr = *(const short8*)&WT[((lane & 15) + 16 * tt) * KP + quad * 8];
        acc[tt] = __builtin_amdgcn_mfma_f32_16x16x32_bf16(a, bfr, acc[tt], 0, 0, 0);
    }

    if (CIN == 34) {
        float x32[4], x33[4];
#pragma unroll
        for (int r = 0; r < 4; ++r) {
            int row = row0 + quad * 4 + r; if (row >= M) row = M - 1;
            x32[r] = ldf(X, row * CIN + 32, bf);
            x33[r] = ldf(X, row * CIN + 33, bf);
        }
#pragma unroll
        for (int tt = 0; tt < 4; ++tt) {
            int col = (lane & 15) + 16 * tt;
            float w32 = bs2f(WT[col * KP + 32]);
            float w33 = bs2f(WT[col * KP + 33]);
#pragma unroll
            for (int r = 0; r < 4; ++r)
                acc[tt][r] += x32[r] * w32 + x33[r] * w33;
        }
    }

#pragma unroll
    for (int tt = 0; tt < 4; ++tt) {
        int col = (lane & 15) + 16 * tt;
        float bb = bl[col];
#pragma unroll
        for (int r = 0; r < 4; ++r) {
            int row = row0 + quad * 4 + r;
            if (row < M) {
                float v = acc[tt][r] + bb;
                v = v > 0.f ? v : 0.01f * v;
                Y[(size_t)row * 64 + col] = __float2bfloat16(v);
            }
        }
    }
}

// merged: both input projections in one dispatch (block-uniform branch)
__global__ __launch_bounds__(256) void k_in_proj_all(
    const void* __restrict__ Xb, const void* __restrict__ Wb, const void* __restrict__ Bb,
    bf16* __restrict__ Yb, int MB,
    const void* __restrict__ Xp, const void* __restrict__ Wp, const void* __restrict__ Bp,
    bf16* __restrict__ Yp, int MP, const int* __restrict__ flag)
{
    const int bf = *flag;
    __shared__ short WT[64 * 40];
    __shared__ float bl[64];
    int nbb = (MB + 63) >> 6;
    if (blockIdx.x < nbb) in_proj_body<32>(WT, bl, blockIdx.x, Xb, Wb, Bb, Yb, MB, bf);
    else                  in_proj_body<34>(WT, bl, blockIdx.x - nbb, Xp, Wp, Bp, Yp, MP, bf);
}

// ---- MFMA dual GAT projection body ----------------------------------------
template <int N1, int N2, bool S1F, bool S2F>
static __device__ __forceinline__ void dual_body(
    short* WT, int bid, const bf16* __restrict__ H,
    const void* __restrict__ W1, const void* __restrict__ W2,
    const void* __restrict__ as1, const void* __restrict__ ad1,
    const void* __restrict__ as2, const void* __restrict__ ad2,
    bf16* __restrict__ HS1, bf16* __restrict__ HS2,
    float* __restrict__ SS1, float* __restrict__ SD1,
    float* __restrict__ SS2, float* __restrict__ SD2,
    int M, int bf)
{
    constexpr int KP = 72;
    constexpr int T1 = N1 / 16, T2 = N2 / 16, T = T1 + T2;
    for (int i = threadIdx.x; i < N1 * 64; i += 256) {
        int n = i >> 6, k = i & 63;
        WT[n * KP + k] = f2bs(ldf(W1, k * N1 + n, bf));
    }
    for (int i = threadIdx.x; i < N2 * 64; i += 256) {
        int n = i >> 6, k = i & 63;
        WT[(N1 + n) * KP + k] = f2bs(ldf(W2, k * N2 + n, bf));
    }
    __syncthreads();

    int lane = threadIdx.x & 63;
    int wv   = threadIdx.x >> 6;
    int m = lane & 15, quad = lane >> 4;
    int row0 = (bid * 4 + wv) * 16;
    if (row0 >= M) return;

    const short* Hs = (const short*)H;
    int arow = row0 + m; if (arow >= M) arow = M - 1;

    f32x4 acc[T] = {};
#pragma unroll
    for (int ks = 0; ks < 2; ++ks) {
        short8 a = *(const short8*)&Hs[(size_t)arow * 64 + ks * 32 + quad * 8];
#pragma unroll
        for (int tt = 0; tt < T; ++tt) {
            short8 bfr = *(const short8*)&WT[((lane & 15) + 16 * tt) * KP + ks * 32 + quad * 8];
            acc[tt] = __builtin_amdgcn_mfma_f32_16x16x32_bf16(a, bfr, acc[tt], 0, 0, 0);
        }
    }

    float vs1[4] = {}, vd1[4] = {}, vs2[4] = {}, vd2[4] = {};
#pragma unroll
    for (int tt = 0; tt < T1; ++tt) {
        int col = (lane & 15) + 16 * tt;
        float av = ldf(as1, col, bf), dv = ldf(ad1, col, bf);
#pragma unroll
        for (int r = 0; r < 4; ++r) {
            vs1[r] += acc[tt][r] * av;
            vd1[r] += acc[tt][r] * dv;
        }
    }
#pragma unroll
    for (int tt = 0; tt < T2; ++tt) {
        int col = (lane & 15) + 16 * tt;
        float av = ldf(as2, col, bf), dv = ldf(ad2, col, bf);
#pragma unroll
        for (int r = 0; r < 4; ++r) {
            vs2[r] += acc[T1 + tt][r] * av;
            vd2[r] += acc[T1 + tt][r] * dv;
        }
    }
#pragma unroll
    for (int off = 1; off < 16; off <<= 1)
#pragma unroll
        for (int r = 0; r < 4; ++r) {
            vs1[r] += __shfl_xor(vs1[r], off);
            vd1[r] += __shfl_xor(vd1[r], off);
            vs2[r] += __shfl_xor(vs2[r], off);
            vd2[r] += __shfl_xor(vd2[r], off);
        }
    int c = lane & 15;
    {
        int row = row0 + quad * 4 + (c & 3);
        if (row < M) {
            if (c < 4)       SS1[row] = sel4(vs1, c & 3);
            else if (c < 8)  SD1[row] = sel4(vd1, c & 3);
            else if (c < 12) SS2[row] = sel4(vs2, c & 3);
            else             SD2[row] = sel4(vd2, c & 3);
        }
    }

    if (S1F) {
#pragma unroll
        for (int tt = 0; tt < T1; ++tt) {
            int col = (lane & 15) + 16 * tt;
#pragma unroll
            for (int r = 0; r < 4; ++r) {
                int row = row0 + quad * 4 + r;
                if (row < M)
                    HS1[(size_t)row * N1 + col] = __float2bfloat16(acc[tt][r]);
            }
        }
    }
    if (S2F) {
#pragma unroll
        for (int tt = 0; tt < T2; ++tt) {
            int col = (lane & 15) + 16 * tt;
#pragma unroll
            for (int r = 0; r < 4; ++r) {
                int row = row0 + quad * 4 + r;
                if (row < M)
                    HS2[(size_t)row * N2 + col] = __float2bfloat16(acc[T1 + tt][r]);
            }
        }
    }
}

// ---- MFMA single GAT projection body --------------------------------------
template <int N, bool STORE>
static __device__ __forceinline__ void proj_body(
    short* WT, int bid, const bf16* __restrict__ H, const void* __restrict__ W,
    const void* __restrict__ a_s, const void* __restrict__ a_d,
    bf16* __restrict__ HS, float* __restrict__ SS, float* __restrict__ SD,
    int M, int bf)
{
    constexpr int KP = 72;
    constexpr int T = N / 16;
    for (int i = threadIdx.x; i < N * 64; i += 256) {
        int n = i >> 6, k = i & 63;
        WT[n * KP + k] = f2bs(ldf(W, k * N + n, bf));
    }
    __syncthreads();

    int lane = threadIdx.x & 63;
    int wv   = threadIdx.x >> 6;
    int m = lane & 15, quad = lane >> 4;
    int row0 = (bid * 4 + wv) * 16;
    if (row0 >= M) return;

    const short* Hs = (const short*)H;
    int arow = row0 + m; if (arow >= M) arow = M - 1;

    f32x4 acc[T] = {};
#pragma unroll
    for (int ks = 0; ks < 2; ++ks) {
        short8 a = *(const short8*)&Hs[(size_t)arow * 64 + ks * 32 + quad * 8];
#pragma unroll
        for (int tt = 0; tt < T; ++tt) {
            short8 bfr = *(const short8*)&WT[((lane & 15) + 16 * tt) * KP + ks * 32 + quad * 8];
            acc[tt] = __builtin_amdgcn_mfma_f32_16x16x32_bf16(a, bfr, acc[tt], 0, 0, 0);
        }
    }

    float asv[T], adv[T];
#pragma unroll
    for (int tt = 0; tt < T; ++tt) {
        int col = (lane & 15) + 16 * tt;
        asv[tt] = ldf(a_s, col, bf);
        adv[tt] = ldf(a_d, col, bf);
    }
    float vs[4] = {}, vd[4] = {};
#pragma unroll
    for (int tt = 0; tt < T; ++tt)
#pragma unroll
        for (int r = 0; r < 4; ++r) {
            vs[r] += acc[tt][r] * asv[tt];
            vd[r] += acc[tt][r] * adv[tt];
        }
#pragma unroll
    for (int off = 1; off < 16; off <<= 1)
#pragma unroll
        for (int r = 0; r < 4; ++r) {
            vs[r] += __shfl_xor(vs[r], off);
            vd[r] += __shfl_xor(vd[r], off);
        }
    int c = lane & 15;
    if (c < 8) {
        int row = row0 + quad * 4 + (c & 3);
        if (row < M) {
            if (c < 4) SS[row] = sel4(vs, c & 3);
            else       SD[row] = sel4(vd, c & 3);
        }
    }

    if (STORE) {
#pragma unroll
        for (int tt = 0; tt < T; ++tt) {
            int col = (lane & 15) + 16 * tt;
#pragma unroll
            for (int r = 0; r < 4; ++r) {
                int row = row0 + quad * 4 + r;
                if (row < M)
                    HS[(size_t)row * N + col] = __float2bfloat16(acc[tt][r]);
            }
        }
    }
}

// merged conv1 duals: hb @ [W_bb1|Ws_bp1] and hp @ [W_pp1|Wd_bp1]
__global__ __launch_bounds__(256) void k_dual64_all(
    const bf16* __restrict__ hb,
    const void* W_bb1, const void* Ws_bp1,
    const void* as_bb1, const void* ad_bb1, const void* as_bp1, const void* ad_bp1,
    bf16* hs_bb, bf16* hs_bp,
    float* ss_bb, float* sd_bb, float* ss_bp, float* junkNB, int MB,
    const bf16* __restrict__ hp,
    const void* W_pp1, const void* Wd_bp1,
    const void* as_pp1, const void* ad_pp1,
    bf16* hs_pp, float* ss_pp, float* sd_pp, float* junkNP, float* sd_bp, int MP,
    const int* __restrict__ flag)
{
    const int bf = *flag;
    __shared__ short WT[128 * 72];
    int nbb = (MB + 63) >> 6;
    if (blockIdx.x < nbb)
        dual_body<64, 64, true, true>(WT, blockIdx.x, hb, W_bb1, Ws_bp1,
            as_bb1, ad_bb1, as_bp1, ad_bp1, hs_bb, hs_bp,
            ss_bb, sd_bb, ss_bp, junkNB, MB, bf);
    else
        dual_body<64, 64, true, false>(WT, blockIdx.x - nbb, hp, W_pp1, Wd_bp1,
            as_pp1, ad_pp1, as_bp1, ad_bp1, hs_pp, nullptr,
            ss_pp, sd_pp, junkNP, sd_bp, MP, bf);
}

// merged conv2 projections: hp2 dual32 + hb2 single32
__global__ __launch_bounds__(256) void k_proj2_all(
    const bf16* __restrict__ hp2,
    const void* W_pp2, const void* Wd_bp2,
    const void* as_pp2, const void* ad_pp2, const void* as_bp2, const void* ad_bp2,
    bf16* hs2_pp, float* ss2_pp, float* sd2_pp, float* junkNP, float* sd2_bp, int MP,
    const bf16* __restrict__ hb2,
    const void* Ws_bp2, bf16* hs2_bp, float* ss2_bp, float* junkNB, int MB,
    const int* __restrict__ flag)
{
    const int bf = *flag;
    __shared__ short WT[64 * 72];
    int npb = (MP + 63) >> 6;
    if (blockIdx.x < npb)
        dual_body<32, 32, true, false>(WT, blockIdx.x, hp2, W_pp2, Wd_bp2,
            as_pp2, ad_pp2, as_bp2, ad_bp2, hs2_pp, nullptr,
            ss2_pp, sd2_pp, junkNP, sd2_bp, MP, bf);
    else
        proj_body<32, true>(WT, blockIdx.x - npb, hb2, Ws_bp2,
            as_bp2, ad_bp2, hs2_bp, ss2_bp, junkNB, MB, bf);
}

// ---- gather bodies (round-8 2-cols/lane versions) -------------------------
static __device__ __forceinline__ void gather1_body(
    int bid, const int* __restrict__ ip, const int* __restrict__ si,
    const float* __restrict__ SS, const float* __restrict__ SD,
    const bf16* __restrict__ HS, const void* __restrict__ bias,
    bf16* __restrict__ OUT, int M, int bf)
{
    int lane = threadIdx.x & 63;
    int half = lane >> 5, hl = lane & 31;
    int d = bid * 4 + (threadIdx.x >> 6);
    if (d >= M) return;
    const u32* H32 = (const u32*)HS;
    float sdd = SD[d];
    float ax = 0.f, ay = 0.f, den = 0.f;
    if (half == 0) {
        float ex = __expf(lrelu2(SS[d] + sdd));
        u32 h = H32[(size_t)d * 32 + hl];
        ax = lo16(h) * ex; ay = hi16(h) * ex; den = ex;
    }
    int j1 = ip[d + 1];
    int j = ip[d] + half;
    for (; j + 2 < j1; j += 4) {
        int s0 = si[j], s1 = si[j + 2];
        u32 h0 = H32[(size_t)s0 * 32 + hl];
        u32 h1 = H32[(size_t)s1 * 32 + hl];
        float e0 = __expf(lrelu2(SS[s0] + sdd));
        float e1 = __expf(lrelu2(SS[s1] + sdd));
        ax += lo16(h0) * e0 + lo16(h1) * e1;
        ay += hi16(h0) * e0 + hi16(h1) * e1;
        den += e0 + e1;
    }
    if (j < j1) {
        int s0 = si[j];
        u32 h0 = H32[(size_t)s0 * 32 + hl];
        float e0 = __expf(lrelu2(SS[s0] + sdd));
        ax += lo16(h0) * e0; ay += hi16(h0) * e0; den += e0;
    }
    ax += __shfl_xor(ax, 32); ay += __shfl_xor(ay, 32); den += __shfl_xor(den, 32);
    if (half == 0) {
        float vx = ax / den + ldf(bias, 2 * hl, bf);
        float vy = ay / den + ldf(bias, 2 * hl + 1, bf);
        vx = vx > 0.f ? vx : 0.01f * vx;
        vy = vy > 0.f ? vy : 0.01f * vy;
        ((u32*)OUT)[(size_t)d * 32 + hl] = pack2(vx, vy);
    }
}

static __device__ __forceinline__ void gather2_body(
    int bid, const int* __restrict__ ip1, const int* __restrict__ si,
    const float* __restrict__ SS1, const float* __restrict__ SD1,
    const bf16* __restrict__ HS1,
    const int* __restrict__ ip2,
    const float* __restrict__ SS2, const float* __restrict__ SD2,
    const bf16* __restrict__ HS2,
    const void* __restrict__ b1, const void* __restrict__ b2,
    bf16* __restrict__ OUT, int M, int bf)
{
    int lane = threadIdx.x & 63;
    int half = lane >> 5, hl = lane & 31;
    int d = bid * 4 + (threadIdx.x >> 6);
    if (d >= M) return;
    const u32* H1 = (const u32*)HS1;
    const u32* H2 = (const u32*)HS2;
    float sdd = SD1[d];
    float a1x = 0.f, a1y = 0.f, den1 = 0.f;
    if (half == 0) {
        float ex = __expf(lrelu2(SS1[d] + sdd));
        u32 h = H1[(size_t)d * 32 + hl];
        a1x = lo16(h) * ex; a1y = hi16(h) * ex; den1 = ex;
    }
    int j1 = ip1[d + 1];
    int j = ip1[d] + half;
    for (; j + 2 < j1; j += 4) {
        int s0 = si[j], s1 = si[j + 2];
        u32 h0 = H1[(size_t)s0 * 32 + hl];
        u32 h1 = H1[(size_t)s1 * 32 + hl];
        float e0 = __expf(lrelu2(SS1[s0] + sdd));
        float e1 = __expf(lrelu2(SS1[s1] + sdd));
        a1x += lo16(h0) * e0 + lo16(h1) * e1;
        a1y += hi16(h0) * e0 + hi16(h1) * e1;
        den1 += e0 + e1;
    }
    if (j < j1) {
        int s0 = si[j];
        u32 h0 = H1[(size_t)s0 * 32 + hl];
        float e0 = __expf(lrelu2(SS1[s0] + sdd));
        a1x += lo16(h0) * e0; a1y += hi16(h0) * e0; den1 += e0;
    }
    float sdd2 = SD2[d];
    float a2x = 0.f, a2y = 0.f, den2 = 0.f;
    j1 = ip2[d + 1];
    j = ip2[d] + half;
    for (; j + 2 < j1; j += 4) {
        int s0 = si[j], s1 = si[j + 2];
        u32 h0 = H2[(size_t)s0 * 32 + hl];
        u32 h1 = H2[(size_t)s1 * 32 + hl];
        float e0 = __expf(lrelu2(SS2[s0] + sdd2));
        float e1 = __expf(lrelu2(SS2[s1] + sdd2));
        a2x += lo16(h0) * e0 + lo16(h1) * e1;
        a2y += hi16(h0) * e0 + hi16(h1) * e1;
        den2 += e0 + e1;
    }
    if (j < j1) {
        int s0 = si[j];
        u32 h0 = H2[(size_t)s0 * 32 + hl];
        float e0 = __expf(lrelu2(SS2[s0] + sdd2));
        a2x += lo16(h0) * e0; a2y += hi16(h0) * e0; den2 += e0;
    }
    a1x += __shfl_xor(a1x, 32); a1y += __shfl_xor(a1y, 32); den1 += __shfl_xor(den1, 32);
    a2x += __shfl_xor(a2x, 32); a2y += __shfl_xor(a2y, 32); den2 += __shfl_xor(den2, 32);
    if (half == 0) {
        float inv2 = den2 > 0.f ? 1.f / den2 : 0.f;
        float vx = a1x / den1 + a2x * inv2 + ldf(b1, 2 * hl, bf) + ldf(b2, 2 * hl, bf);
        float vy = a1y / den1 + a2y * inv2 + ldf(b1, 2 * hl + 1, bf) + ldf(b2, 2 * hl + 1, bf);
        vx = vx > 0.f ? vx : 0.01f * vx;
        vy = vy > 0.f ? vy : 0.01f * vy;
        ((u32*)OUT)[(size_t)d * 32 + hl] = pack2(vx, vy);
    }
}

// merged conv1 gathers: bb-dst (gather1) + p-dst (gather2) in one dispatch
__global__ __launch_bounds__(256) void k_gather12(
    const int* __restrict__ ip_bb, const int* __restrict__ si,
    const float* __restrict__ ss_bb, const float* __restrict__ sd_bb,
    const bf16* __restrict__ hs_bb, const void* __restrict__ b_bb1,
    bf16* __restrict__ hb2, int NB,
    const int* __restrict__ ip_pp, const int* __restrict__ ip_bp,
    const float* __restrict__ ss_pp, const float* __restrict__ sd_pp,
    const bf16* __restrict__ hs_pp,
    const float* __restrict__ ss_bp, const float* __restrict__ sd_bp,
    const bf16* __restrict__ hs_bp,
    const void* __restrict__ b_pp1, const void* __restrict__ b_bp1,
    bf16* __restrict__ hp2, int NP,
    const int* __restrict__ flag)
{
    const int bf = *flag;
    int nbb = (NB + 3) >> 2;
    if (blockIdx.x < nbb)
        gather1_body(blockIdx.x, ip_bb, si, ss_bb, sd_bb, hs_bb, b_bb1, hb2, NB, bf);
    else
        gather2_body(blockIdx.x - nbb, ip_pp, si, ss_pp, sd_pp, hs_pp,
                     ip_bp, ss_bp, sd_bp, hs_bp, b_pp1, b_bp1, hp2, NP, bf);
}

// ---- conv2 gather (C=32) + output head ------------------------------------
__global__ __launch_bounds__(256) void k_gather_out(
    const int* __restrict__ ip1, const int* __restrict__ si,
    const float* __restrict__ SS1, const float* __restrict__ SD1,
    const bf16* __restrict__ HS1,
    const int* __restrict__ ip2,
    const float* __restrict__ SS2, const float* __restrict__ SD2,
    const bf16* __restrict__ HS2,
    const void* __restrict__ b1, const void* __restrict__ b2,
    const void* __restrict__ Wout, const void* __restrict__ bout,
    void* __restrict__ OUT, int M, const int* __restrict__ flag)
{
    const int bf = *flag;
    int lane = threadIdx.x & 63;
    int q = lane >> 4, hl = lane & 15;
    int d = blockIdx.x * 4 + (threadIdx.x >> 6);
    if (d >= M) return;
    const u32* H1 = (const u32*)HS1;
    const u32* H2 = (const u32*)HS2;
    float sdd = SD1[d];
    float a1x = 0.f, a1y = 0.f, den1 = 0.f;
    if (q == 0) {
        float ex = __expf(lrelu2(SS1[d] + sdd));
        u32 h = H1[(size_t)d * 16 + hl];
        a1x = lo16(h) * ex; a1y = hi16(h) * ex; den1 = ex;
    }
    int j1 = ip1[d + 1];
    for (int j = ip1[d] + q; j < j1; j += 4) {
        int s0 = si[j];
        u32 h0 = H1[(size_t)s0 * 16 + hl];
        float e0 = __expf(lrelu2(SS1[s0] + sdd));
        a1x += lo16(h0) * e0; a1y += hi16(h0) * e0; den1 += e0;
    }
    float sdd2 = SD2[d];
    float a2x = 0.f, a2y = 0.f, den2 = 0.f;
    j1 = ip2[d + 1];
    for (int j = ip2[d] + q; j < j1; j += 4) {
        int s0 = si[j];
        u32 h0 = H2[(size_t)s0 * 16 + hl];
        float e0 = __expf(lrelu2(SS2[s0] + sdd2));
        a2x += lo16(h0) * e0; a2y += hi16(h0) * e0; den2 += e0;
    }
    a1x += __shfl_xor(a1x, 16); a1y += __shfl_xor(a1y, 16); den1 += __shfl_xor(den1, 16);
    a2x += __shfl_xor(a2x, 16); a2y += __shfl_xor(a2y, 16); den2 += __shfl_xor(den2, 16);
    a1x += __shfl_xor(a1x, 32); a1y += __shfl_xor(a1y, 32); den1 += __shfl_xor(den1, 32);
    a2x += __shfl_xor(a2x, 32); a2y += __shfl_xor(a2y, 32); den2 += __shfl_xor(den2, 32);
    float inv2 = den2 > 0.f ? 1.f / den2 : 0.f;
    float vx = a1x / den1 + a2x * inv2 + ldf(b1, 2 * hl, bf) + ldf(b2, 2 * hl, bf);
    float vy = a1y / den1 + a2y * inv2 + ldf(b1, 2 * hl + 1, bf) + ldf(b2, 2 * hl + 1, bf);
    vx = vx > 0.f ? vx : 0.01f * vx;
    vy = vy > 0.f ? vy : 0.01f * vy;
    float t = vx * ldf(Wout, 2 * hl, bf) + vy * ldf(Wout, 2 * hl + 1, bf);
#pragma unroll
    for (int off = 1; off < 16; off <<= 1) t += __shfl_xor(t, off);
    if (lane == 0) {
        float r = t + ldf(bout, 0, bf);
        if (bf) ((bf16*)OUT)[d] = __float2bfloat16(r);
        else    ((float*)OUT)[d] = r;
    }
}

// ---------------------------------------------------------------------------
extern "C" void kernel_launch(void* const* d_in, const int* in_sizes, int n_in,
                              void* d_out, int out_size, void* d_ws, size_t ws_size,
                              hipStream_t stream)
{
    const void* x_b = d_in[0];
    const void* x_p = d_in[1];
    const int* ei_bb = (const int*)d_in[2];
    const int* ei_pp = (const int*)d_in[3];
    const int* bp_s  = (const int*)d_in[4];
    const int* bp_d  = (const int*)d_in[5];
    const void *W_in_b = d_in[6],  *b_in_b = d_in[7];
    const void *W_in_p = d_in[8],  *b_in_p = d_in[9];
    const void *W_bb1 = d_in[10], *as_bb1 = d_in[11], *ad_bb1 = d_in[12], *b_bb1 = d_in[13];
    const void *W_pp1 = d_in[14], *as_pp1 = d_in[15], *ad_pp1 = d_in[16], *b_pp1 = d_in[17];
    const void *Ws_bp1 = d_in[18], *Wd_bp1 = d_in[19], *as_bp1 = d_in[20], *ad_bp1 = d_in[21], *b_bp1 = d_in[22];
    // d_in[23..26] = conv2 b->b params: dead code in reference
    const void *W_pp2 = d_in[27], *as_pp2 = d_in[28], *ad_pp2 = d_in[29], *b_pp2 = d_in[30];
    const void *Ws_bp2 = d_in[31], *Wd_bp2 = d_in[32], *as_bp2 = d_in[33], *ad_bp2 = d_in[34], *b_bp2 = d_in[35];
    const void *W_out = d_in[36], *b_out = d_in[37];

    const int NB   = in_sizes[0] / 32;
    const int NP   = in_sizes[1] / 34;
    const int E_bb = in_sizes[2] / 2;
    const int E_pp = in_sizes[3] / 2;
    const int E_bp = in_sizes[4];
    const int E_all = E_bb + E_pp + E_bp;
    const int NALL  = NB + 2 * NP;
    const int* bb_s = ei_bb;  const int* bb_d = ei_bb + E_bb;
    const int* pp_s = ei_pp;  const int* pp_d = ei_pp + E_pp;
    (void)ws_size; (void)n_in; (void)out_size;

    const int nbkt  = (NALL + (1 << ABITS) - 1) >> ABITS;
    const int nblk  = (E_all + CHUNKE - 1) / CHUNKE;
    const int nh    = nbkt * nblk;

    char* base = (char*)d_ws;
    size_t o = 0;
    auto alloc = [&](size_t bytes) { char* p = base + o; o += (bytes + 255) & ~(size_t)255; return p; };

    // --- small persistent ---
    int* flag  = (int*)alloc(256);
    int* bsum  = (int*)alloc(1024 * 4);
    int* histM = (int*)alloc((size_t)nh * 4);
    int* histS = (int*)alloc((size_t)(nh + 1) * 4);
    int* ip_all = (int*)alloc((size_t)(NALL + 1) * 4);
    unsigned* ebuf = (unsigned*)alloc((size_t)E_all * 4);
    int* si_all = (int*)alloc((size_t)E_all * 4);
    float* ss_bb = (float*)alloc((size_t)NB * 4);
    float* sd_bb = (float*)alloc((size_t)NB * 4);
    float* ss_bp = (float*)alloc((size_t)NB * 4);
    float* ss_pp = (float*)alloc((size_t)NP * 4);
    float* sd_pp = (float*)alloc((size_t)NP * 4);
    float* sd_bp = (float*)alloc((size_t)NP * 4);
    float* ss2_bp = ss_bb;   // ss_bb dead after k_gather12
    float* ss2_pp = ss_pp;   // conv1 p-scores dead after k_gather12
    float* sd2_pp = sd_pp;
    float* sd2_bp = sd_bp;
    float* junkNB = (float*)ebuf;            // ebuf dead after k_finalize
    float* junkNP = (float*)ebuf + NB;

    // --- feature slots (liveness re-verified for merged kernels) ---
    // S1: hb -> hs2_bp          (hb dead after k_dual64_all)
    // S2: hp -> hp2             (hp dead after k_dual64_all; hp2 written by gather12 branch B)
    // S3: hs_bb -> hs2_pp       (hs_bb dead after k_gather12)
    // S4: hb2
    // S5: hs_bp
    // S6: hs_pp
    char* S1 = alloc((size_t)NB * 64 * 2);
    char* S2 = alloc((size_t)NP * 64 * 2);
    char* S3 = alloc((size_t)NB * 64 * 2);
    char* S4 = alloc((size_t)NB * 64 * 2);
    char* S5 = alloc((size_t)NB * 64 * 2);
    char* S6 = alloc((size_t)NP * 64 * 2);

    bf16* hb     = (bf16*)S1;
    bf16* hp     = (bf16*)S2;
    bf16* hs_bb  = (bf16*)S3;
    bf16* hb2    = (bf16*)S4;
    bf16* hs_bp  = (bf16*)S5;
    bf16* hs_pp  = (bf16*)S6;
    bf16* hp2    = (bf16*)S2;
    bf16* hs2_pp = (bf16*)S3;
    bf16* hs2_bp = (bf16*)S1;

    auto cdiv = [](int a, int b) { return (a + b - 1) / b; };

    // 1. CSR build (probe fused into hist block 0)
    k_bkt_hist<<<nblk, 256, 0, stream>>>(bb_d, pp_d, bp_d, histM,
                                         (const unsigned*)x_b, flag,
                                         E_bb, E_pp, E_bp, NB, NP, nbkt, nblk);
    int sb1 = cdiv(nh, 1024);
    k_scan1<<<sb1, 1024, 0, stream>>>(histM, histS, bsum, nh);
    k_scan2<<<1, 1024, 0, stream>>>(bsum, sb1);
    k_scan3<<<sb1, 1024, 0, stream>>>(histS, bsum, nh, E_all);
    k_bkt_scatter<<<nblk, 256, 0, stream>>>(bb_s, bb_d, pp_s, pp_d, bp_s, bp_d,
                                            histS, ebuf, E_bb, E_pp, E_bp, NB, NP, nbkt, nblk);
    k_finalize<<<nbkt, 256, 0, stream>>>(ebuf, histS, ip_all, si_all, NALL, E_all, nbkt, nblk);

    const int* ip_bb = ip_all;
    const int* ip_pp = ip_all + NB;
    const int* ip_bp = ip_all + NB + NP;

    // 2. input projections (merged)
    k_in_proj_all<<<cdiv(NB, 64) + cdiv(NP, 64), 256, 0, stream>>>(
        x_b, W_in_b, b_in_b, hb, NB, x_p, W_in_p, b_in_p, hp, NP, flag);

    // 3. conv1 dual projections (merged)
    k_dual64_all<<<cdiv(NB, 64) + cdiv(NP, 64), 256, 0, stream>>>(
        hb, W_bb1, Ws_bp1, as_bb1, ad_bb1, as_bp1, ad_bp1,
        hs_bb, hs_bp, ss_bb, sd_bb, ss_bp, junkNB, NB,
        hp, W_pp1, Wd_bp1, as_pp1, ad_pp1,
        hs_pp, ss_pp, sd_pp, junkNP, sd_bp, NP, flag);

    // 4. conv1 gathers (merged single dispatch; hb2 <- bb, hp2 <- pp+bp)
    k_gather12<<<cdiv(NB, 4) + cdiv(NP, 4), 256, 0, stream>>>(
        ip_bb, si_all, ss_bb, sd_bb, hs_bb, b_bb1, hb2, NB,
        ip_pp, ip_bp, ss_pp, sd_pp, hs_pp, ss_bp, sd_bp, hs_bp,
        b_pp1, b_bp1, hp2, NP, flag);

    // 5. conv2 projections (merged)
    k_proj2_all<<<cdiv(NP, 64) + cdiv(NB, 64), 256, 0, stream>>>(
        hp2, W_pp2, Wd_bp2, as_pp2, ad_pp2, as_bp2, ad_bp2,
        hs2_pp, ss2_pp, sd2_pp, junkNP, sd2_bp, NP,
        hb2, Ws_bp2, hs2_bp, ss2_bp, junkNB, NB, flag);

    // 6. conv2 gather + output head
    k_gather_out<<<cdiv(NP, 4), 256, 0, stream>>>(
        ip_pp, si_all, ss2_pp, sd2_pp, hs2_pp,
        ip_bp, ss2_bp, sd2_bp, hs2_bp,
        b_pp2, b_bp2, W_out, b_out, d_out, NP, flag);
}

// Round 10
// 396.655 us; speedup vs baseline: 1.0944x; 1.0284x over previous
//
#include <hip/hip_runtime.h>
#include <hip/hip_bf16.h>
#include <cstdint>
#include <cstddef>

// ---------------------------------------------------------------------------
// HeteroGNN (2-layer hetero GAT) on MI355X, gfx950.  Round 10.
//  - CSR build overlapped with projections via grid-split merges:
//      A: bucket-hist blocks ∥ input-projection blocks (per-block inline
//         dtype probe removes the flag dependency inside the dispatch)
//      E: bucket-scatter blocks ∥ conv1 dual-projection blocks
//  - k_finalize now also emits per-edge softmax weights
//    w[p] = exp(lrelu_0.2(ss[src]+sd[dst])) aligned with sidx (conv1 scores
//    are ready: finalize runs after scatter∥dual64).  Conv1 gathers stream
//    w[] instead of random SS loads + exp -> shorter dependent chain.
//  - Dispatches: 11 -> 9.
//  - MFMA projections, LDS-bucket CSR, softmax max-drop, dead conv2-b->b
//    skip: retained.
// ---------------------------------------------------------------------------

typedef __attribute__((ext_vector_type(8))) short short8;   // 8 bf16 (4 VGPR)
typedef __attribute__((ext_vector_type(4))) float f32x4;    // MFMA acc
typedef unsigned int u32;
typedef __hip_bfloat16 bf16;

#define ABITS 9             // bucket = concat_dst >> ABITS  (512 dsts/bucket)
#define CHUNKE 8192         // edges per block in bucket passes

static __device__ __forceinline__ float b2f(bf16 v) { return __bfloat162float(v); }

static __device__ __forceinline__ float ldf(const void* p, int i, int bf) {
    return bf ? __bfloat162float(((const bf16*)p)[i]) : ((const float*)p)[i];
}

static __device__ __forceinline__ short f2bs(float f) {
    bf16 h = __float2bfloat16(f);
    return *reinterpret_cast<short*>(&h);
}
static __device__ __forceinline__ float bs2f(short s) {
    bf16 h = *reinterpret_cast<bf16*>(&s);
    return __bfloat162float(h);
}
static __device__ __forceinline__ float lo16(u32 u) { return bs2f((short)(u & 0xffffu)); }
static __device__ __forceinline__ float hi16(u32 u) { return bs2f((short)(u >> 16)); }
static __device__ __forceinline__ u32 pack2(float x, float y) {
    return (u32)(unsigned short)f2bs(x) | ((u32)(unsigned short)f2bs(y) << 16);
}
static __device__ __forceinline__ float sel4(const float* a, int i) {
    return i == 0 ? a[0] : i == 1 ? a[1] : i == 2 ? a[2] : a[3];
}
static __device__ __forceinline__ float lrelu2(float x) { return x > 0.f ? x : 0.2f * x; }

// per-block inline dtype probe (4 KB of x_b, L2-hot after first block)
static __device__ __forceinline__ int probe_bf(const unsigned* __restrict__ w, int* cnt) {
    if (threadIdx.x == 0) *cnt = 0;
    __syncthreads();
    int c = 0;
#pragma unroll
    for (int j = 0; j < 4; ++j) {
        unsigned u = w[threadIdx.x * 4 + j];
        unsigned e = (u >> 7) & 0xffu;
        c += (e >= 100u && e <= 145u) ? 1 : 0;
    }
    atomicAdd(cnt, c);
    __syncthreads();
    int r = (*cnt > 614) ? 1 : 0;
    __syncthreads();
    return r;
}

// ---- MFMA input projection body -------------------------------------------
template <int CIN>
static __device__ __forceinline__ void in_proj_body(
    short* WT, float* bl, int bid,
    const void* __restrict__ X, const void* __restrict__ W, const void* __restrict__ B,
    bf16* __restrict__ Y, int M, int bf)
{
    constexpr int KP = 40;
    for (int i = threadIdx.x; i < 64 * CIN; i += 256) {
        int n = i / CIN, k = i - n * CIN;
        WT[n * KP + k] = f2bs(ldf(W, k * 64 + n, bf));
    }
    if (threadIdx.x < 64) bl[threadIdx.x] = ldf(B, threadIdx.x, bf);
    __syncthreads();

    int lane = threadIdx.x & 63;
    int wv   = threadIdx.x >> 6;
    int m = lane & 15, quad = lane >> 4;
    int row0 = (bid * 4 + wv) * 16;
    if (row0 >= M) return;

    int arow = row0 + m; if (arow >= M) arow = M - 1;
    short8 a;
#pragma unroll
    for (int j = 0; j < 8; ++j)
        a[j] = f2bs(ldf(X, arow * CIN + quad * 8 + j, bf));

    f32x4 acc[4] = {};
#pragma unroll
    for (int tt = 0; tt < 4; ++tt) {
        short8 bfr = *(const short8*)&WT[((lane & 15) + 16 * tt) * KP + quad * 8];
        acc[tt] = __builtin_amdgcn_mfma_f32_16x16x32_bf16(a, bfr, acc[tt], 0, 0, 0);
    }

    if (CIN == 34) {
        float x32[4], x33[4];
#pragma unroll
        for (int r = 0; r < 4; ++r) {
            int row = row0 + quad * 4 + r; if (row >= M) row = M - 1;
            x32[r] = ldf(X, row * CIN + 32, bf);
            x33[r] = ldf(X, row * CIN + 33, bf);
        }
#pragma unroll
        for (int tt = 0; tt < 4; ++tt) {
            int col = (lane & 15) + 16 * tt;
            float w32 = bs2f(WT[col * KP + 32]);
            float w33 = bs2f(WT[col * KP + 33]);
#pragma unroll
            for (int r = 0; r < 4; ++r)
                acc[tt][r] += x32[r] * w32 + x33[r] * w33;
        }
    }

#pragma unroll
    for (int tt = 0; tt < 4; ++tt) {
        int col = (lane & 15) + 16 * tt;
        float bb = bl[col];
#pragma unroll
        for (int r = 0; r < 4; ++r) {
            int row = row0 + quad * 4 + r;
            if (row < M) {
                float v = acc[tt][r] + bb;
                v = v > 0.f ? v : 0.01f * v;
                Y[(size_t)row * 64 + col] = __float2bfloat16(v);
            }
        }
    }
}

// ---- A: bucket hist ∥ input projections ----------------------------------
__global__ __launch_bounds__(256) void k_hist_inproj(
    const int* __restrict__ bb_d, const int* __restrict__ pp_d,
    const int* __restrict__ bp_d, int* __restrict__ histM,
    const unsigned* __restrict__ probe_w, int* __restrict__ flag,
    int E_bb, int E_pp, int E_bp, int NB, int NP, int nbkt, int nblk,
    const void* __restrict__ Xb, const void* __restrict__ Wb, const void* __restrict__ Bb,
    bf16* __restrict__ Yb, int MB,
    const void* __restrict__ Xp, const void* __restrict__ Wp, const void* __restrict__ Bp,
    bf16* __restrict__ Yp, int MP)
{
    __shared__ short WT[64 * 40];
    __shared__ float bl[64];
    __shared__ int aux[1 << ABITS];
    if ((int)blockIdx.x < nblk) {
        if (blockIdx.x == 0) {
            int b = probe_bf(probe_w, &aux[0]);
            if (threadIdx.x == 0) *flag = b;
        }
        for (int i = threadIdx.x; i < nbkt; i += 256) aux[i] = 0;
        __syncthreads();
        int E_all = E_bb + E_pp + E_bp;
        int base = blockIdx.x * CHUNKE;
        int end = base + CHUNKE < E_all ? base + CHUNKE : E_all;
        for (int i = base + threadIdx.x; i < end; i += 256) {
            int d;
            if (i < E_bb) d = bb_d[i];
            else if (i < E_bb + E_pp) d = NB + pp_d[i - E_bb];
            else d = NB + NP + bp_d[i - E_bb - E_pp];
            atomicAdd(&aux[d >> ABITS], 1);
        }
        __syncthreads();
        for (int i = threadIdx.x; i < nbkt; i += 256)
            histM[(size_t)i * nblk + blockIdx.x] = aux[i];
    } else {
        int bfv = probe_bf(probe_w, &aux[0]);
        int bid = blockIdx.x - nblk;
        int nbb = (MB + 63) >> 6;
        if (bid < nbb) in_proj_body<32>(WT, bl, bid, Xb, Wb, Bb, Yb, MB, bfv);
        else           in_proj_body<34>(WT, bl, bid - nbb, Xp, Wp, Bp, Yp, MP, bfv);
    }
}

// ---- scans over histM -----------------------------------------------------
__global__ __launch_bounds__(1024) void k_scan1(const int* __restrict__ deg,
                                                int* __restrict__ out,
                                                int* __restrict__ bsum, int n)
{
    __shared__ int wsum[16];
    int gid = blockIdx.x * 1024 + threadIdx.x;
    int lane = threadIdx.x & 63, wid = threadIdx.x >> 6;
    int v = (gid < n) ? deg[gid] : 0;
    int x = v;
#pragma unroll
    for (int off = 1; off < 64; off <<= 1) {
        int y = __shfl_up(x, off, 64);
        if (lane >= off) x += y;
    }
    if (lane == 63) wsum[wid] = x;
    __syncthreads();
    if (wid == 0 && lane < 16) {
        int w0 = wsum[lane];
#pragma unroll
        for (int off = 1; off < 16; off <<= 1) {
            int y = __shfl_up(w0, off, 16);
            if (lane >= off) w0 += y;
        }
        wsum[lane] = w0;
    }
    __syncthreads();
    int base = (wid > 0) ? wsum[wid - 1] : 0;
    int incl = base + x;
    if (gid < n) out[gid] = incl - v;
    if (threadIdx.x == 1023) bsum[blockIdx.x] = incl;
}

__global__ __launch_bounds__(1024) void k_scan2(int* __restrict__ bsum, int nb)
{
    __shared__ int wsum[16];
    int lane = threadIdx.x & 63, wid = threadIdx.x >> 6;
    int v = (threadIdx.x < nb) ? bsum[threadIdx.x] : 0;
    int x = v;
#pragma unroll
    for (int off = 1; off < 64; off <<= 1) {
        int y = __shfl_up(x, off, 64);
        if (lane >= off) x += y;
    }
    if (lane == 63) wsum[wid] = x;
    __syncthreads();
    if (wid == 0 && lane < 16) {
        int w0 = wsum[lane];
#pragma unroll
        for (int off = 1; off < 16; off <<= 1) {
            int y = __shfl_up(w0, off, 16);
            if (lane >= off) w0 += y;
        }
        wsum[lane] = w0;
    }
    __syncthreads();
    int base = (wid > 0) ? wsum[wid - 1] : 0;
    if (threadIdx.x < nb) bsum[threadIdx.x] = base + x - v;
}

__global__ __launch_bounds__(1024) void k_scan3(int* __restrict__ indptr,
                                                const int* __restrict__ bsum,
                                                int n, int E)
{
    int gid = blockIdx.x * 1024 + threadIdx.x;
    if (gid < n) indptr[gid] += bsum[blockIdx.x];
    if (gid == 0) indptr[n] = E;
}

// ---- MFMA dual GAT projection body ----------------------------------------
template <int N1, int N2, bool S1F, bool S2F>
static __device__ __forceinline__ void dual_body(
    short* WT, int bid, const bf16* __restrict__ H,
    const void* __restrict__ W1, const void* __restrict__ W2,
    const void* __restrict__ as1, const void* __restrict__ ad1,
    const void* __restrict__ as2, const void* __restrict__ ad2,
    bf16* __restrict__ HS1, bf16* __restrict__ HS2,
    float* __restrict__ SS1, float* __restrict__ SD1,
    float* __restrict__ SS2, float* __restrict__ SD2,
    int M, int bf)
{
    constexpr int KP = 72;
    constexpr int T1 = N1 / 16, T2 = N2 / 16, T = T1 + T2;
    for (int i = threadIdx.x; i < N1 * 64; i += 256) {
        int n = i >> 6, k = i & 63;
        WT[n * KP + k] = f2bs(ldf(W1, k * N1 + n, bf));
    }
    for (int i = threadIdx.x; i < N2 * 64; i += 256) {
        int n = i >> 6, k = i & 63;
        WT[(N1 + n) * KP + k] = f2bs(ldf(W2, k * N2 + n, bf));
    }
    __syncthreads();

    int lane = threadIdx.x & 63;
    int wv   = threadIdx.x >> 6;
    int m = lane & 15, quad = lane >> 4;
    int row0 = (bid * 4 + wv) * 16;
    if (row0 >= M) return;

    const short* Hs = (const short*)H;
    int arow = row0 + m; if (arow >= M) arow = M - 1;

    f32x4 acc[T] = {};
#pragma unroll
    for (int ks = 0; ks < 2; ++ks) {
        short8 a = *(const short8*)&Hs[(size_t)arow * 64 + ks * 32 + quad * 8];
#pragma unroll
        for (int tt = 0; tt < T; ++tt) {
            short8 bfr = *(const short8*)&WT[((lane & 15) + 16 * tt) * KP + ks * 32 + quad * 8];
            acc[tt] = __builtin_amdgcn_mfma_f32_16x16x32_bf16(a, bfr, acc[tt], 0, 0, 0);
        }
    }

    float vs1[4] = {}, vd1[4] = {}, vs2[4] = {}, vd2[4] = {};
#pragma unroll
    for (int tt = 0; tt < T1; ++tt) {
        int col = (lane & 15) + 16 * tt;
        float av = ldf(as1, col, bf), dv = ldf(ad1, col, bf);
#pragma unroll
        for (int r = 0; r < 4; ++r) {
            vs1[r] += acc[tt][r] * av;
            vd1[r] += acc[tt][r] * dv;
        }
    }
#pragma unroll
    for (int tt = 0; tt < T2; ++tt) {
        int col = (lane & 15) + 16 * tt;
        float av = ldf(as2, col, bf), dv = ldf(ad2, col, bf);
#pragma unroll
        for (int r = 0; r < 4; ++r) {
            vs2[r] += acc[T1 + tt][r] * av;
            vd2[r] += acc[T1 + tt][r] * dv;
        }
    }
#pragma unroll
    for (int off = 1; off < 16; off <<= 1)
#pragma unroll
        for (int r = 0; r < 4; ++r) {
            vs1[r] += __shfl_xor(vs1[r], off);
            vd1[r] += __shfl_xor(vd1[r], off);
            vs2[r] += __shfl_xor(vs2[r], off);
            vd2[r] += __shfl_xor(vd2[r], off);
        }
    int c = lane & 15;
    {
        int row = row0 + quad * 4 + (c & 3);
        if (row < M) {
            if (c < 4)       SS1[row] = sel4(vs1, c & 3);
            else if (c < 8)  SD1[row] = sel4(vd1, c & 3);
            else if (c < 12) SS2[row] = sel4(vs2, c & 3);
            else             SD2[row] = sel4(vd2, c & 3);
        }
    }

    if (S1F) {
#pragma unroll
        for (int tt = 0; tt < T1; ++tt) {
            int col = (lane & 15) + 16 * tt;
#pragma unroll
            for (int r = 0; r < 4; ++r) {
                int row = row0 + quad * 4 + r;
                if (row < M)
                    HS1[(size_t)row * N1 + col] = __float2bfloat16(acc[tt][r]);
            }
        }
    }
    if (S2F) {
#pragma unroll
        for (int tt = 0; tt < T2; ++tt) {
            int col = (lane & 15) + 16 * tt;
#pragma unroll
            for (int r = 0; r < 4; ++r) {
                int row = row0 + quad * 4 + r;
                if (row < M)
                    HS2[(size_t)row * N2 + col] = __float2bfloat16(acc[T1 + tt][r]);
            }
        }
    }
}

// ---- MFMA single GAT projection body --------------------------------------
template <int N, bool STORE>
static __device__ __forceinline__ void proj_body(
    short* WT, int bid, const bf16* __restrict__ H, const void* __restrict__ W,
    const void* __restrict__ a_s, const void* __restrict__ a_d,
    bf16* __restrict__ HS, float* __restrict__ SS, float* __restrict__ SD,
    int M, int bf)
{
    constexpr int KP = 72;
    constexpr int T = N / 16;
    for (int i = threadIdx.x; i < N * 64; i += 256) {
        int n = i >> 6, k = i & 63;
        WT[n * KP + k] = f2bs(ldf(W, k * N + n, bf));
    }
    __syncthreads();

    int lane = threadIdx.x & 63;
    int wv   = threadIdx.x >> 6;
    int m = lane & 15, quad = lane >> 4;
    int row0 = (bid * 4 + wv) * 16;
    if (row0 >= M) return;

    const short* Hs = (const short*)H;
    int arow = row0 + m; if (arow >= M) arow = M - 1;

    f32x4 acc[T] = {};
#pragma unroll
    for (int ks = 0; ks < 2; ++ks) {
        short8 a = *(const short8*)&Hs[(size_t)arow * 64 + ks * 32 + quad * 8];
#pragma unroll
        for (int tt = 0; tt < T; ++tt) {
            short8 bfr = *(const short8*)&WT[((lane & 15) + 16 * tt) * KP + ks * 32 + quad * 8];
            acc[tt] = __builtin_amdgcn_mfma_f32_16x16x32_bf16(a, bfr, acc[tt], 0, 0, 0);
        }
    }

    float asv[T], adv[T];
#pragma unroll
    for (int tt = 0; tt < T; ++tt) {
        int col = (lane & 15) + 16 * tt;
        asv[tt] = ldf(a_s, col, bf);
        adv[tt] = ldf(a_d, col, bf);
    }
    float vs[4] = {}, vd[4] = {};
#pragma unroll
    for (int tt = 0; tt < T; ++tt)
#pragma unroll
        for (int r = 0; r < 4; ++r) {
            vs[r] += acc[tt][r] * asv[tt];
            vd[r] += acc[tt][r] * adv[tt];
        }
#pragma unroll
    for (int off = 1; off < 16; off <<= 1)
#pragma unroll
        for (int r = 0; r < 4; ++r) {
            vs[r] += __shfl_xor(vs[r], off);
            vd[r] += __shfl_xor(vd[r], off);
        }
    int c = lane & 15;
    if (c < 8) {
        int row = row0 + quad * 4 + (c & 3);
        if (row < M) {
            if (c < 4) SS[row] = sel4(vs, c & 3);
            else       SD[row] = sel4(vd, c & 3);
        }
    }

    if (STORE) {
#pragma unroll
        for (int tt = 0; tt < T; ++tt) {
            int col = (lane & 15) + 16 * tt;
#pragma unroll
            for (int r = 0; r < 4; ++r) {
                int row = row0 + quad * 4 + r;
                if (row < M)
                    HS[(size_t)row * N + col] = __float2bfloat16(acc[tt][r]);
            }
        }
    }
}

// ---- E: bucket scatter ∥ conv1 dual projections ---------------------------
__global__ __launch_bounds__(256) void k_scatter_dual(
    const int* __restrict__ bb_s, const int* __restrict__ bb_d,
    const int* __restrict__ pp_s, const int* __restrict__ pp_d,
    const int* __restrict__ bp_s, const int* __restrict__ bp_d,
    const int* __restrict__ histS, unsigned* __restrict__ ebuf,
    int E_bb, int E_pp, int E_bp, int NB, int NP, int nbkt, int nblk,
    const bf16* __restrict__ hb,
    const void* W_bb1, const void* Ws_bp1,
    const void* as_bb1, const void* ad_bb1, const void* as_bp1, const void* ad_bp1,
    bf16* hs_bb, bf16* hs_bp,
    float* ss_bb, float* sd_bb, float* ss_bp, float* junkNB, int MB,
    const bf16* __restrict__ hp,
    const void* W_pp1, const void* Wd_bp1,
    const void* as_pp1, const void* ad_pp1,
    bf16* hs_pp, float* ss_pp, float* sd_pp, float* junkNP, float* sd_bp, int MP,
    const int* __restrict__ flag)
{
    __shared__ short WT[128 * 72];
    if ((int)blockIdx.x < nblk) {
        int* cur = (int*)WT;
        for (int i = threadIdx.x; i < nbkt; i += 256)
            cur[i] = histS[(size_t)i * nblk + blockIdx.x];
        __syncthreads();
        int E_all = E_bb + E_pp + E_bp;
        int base = blockIdx.x * CHUNKE;
        int end = base + CHUNKE < E_all ? base + CHUNKE : E_all;
        for (int i = base + threadIdx.x; i < end; i += 256) {
            int s, d;
            if (i < E_bb) { s = bb_s[i]; d = bb_d[i]; }
            else if (i < E_bb + E_pp) { int j = i - E_bb; s = pp_s[j]; d = NB + pp_d[j]; }
            else { int j = i - E_bb - E_pp; s = bp_s[j]; d = NB + NP + bp_d[j]; }
            int p = atomicAdd(&cur[d >> ABITS], 1);
            ebuf[p] = ((unsigned)(d & ((1 << ABITS) - 1)) << 20) | (unsigned)s;
        }
    } else {
        const int bfv = *flag;
        int bid = blockIdx.x - nblk;
        int nbb = (MB + 63) >> 6;
        if (bid < nbb)
            dual_body<64, 64, true, true>(WT, bid, hb, W_bb1, Ws_bp1,
                as_bb1, ad_bb1, as_bp1, ad_bp1, hs_bb, hs_bp,
                ss_bb, sd_bb, ss_bp, junkNB, MB, bfv);
        else
            dual_body<64, 64, true, false>(WT, bid - nbb, hp, W_pp1, Wd_bp1,
                as_pp1, ad_pp1, as_bp1, ad_bp1, hs_pp, nullptr,
                ss_pp, sd_pp, junkNP, sd_bp, MP, bfv);
    }
}

// ---- F: finalize (deg hist + bucket-local scan + place) + emit edge w -----
__global__ __launch_bounds__(256) void k_finalize(
    const unsigned* __restrict__ ebuf, const int* __restrict__ histS,
    int* __restrict__ ip_all, int* __restrict__ sidx, float* __restrict__ wedge,
    const float* __restrict__ ss_bb, const float* __restrict__ sd_bb,
    const float* __restrict__ ss_pp, const float* __restrict__ sd_pp,
    const float* __restrict__ ss_bp, const float* __restrict__ sd_bp,
    int NB, int NP, int NALL, int E_all, int nbkt, int nblk)
{
    __shared__ int h[1 << ABITS];
    __shared__ int pre[1 << ABITS];
    __shared__ int wq[4];
    int b = blockIdx.x;
    int d0 = b << ABITS;
    int nloc = NALL - d0 < (1 << ABITS) ? NALL - d0 : (1 << ABITS);
    int t = threadIdx.x;
    for (int i = t; i < (1 << ABITS); i += 256) h[i] = 0;
    __syncthreads();
    int s0 = histS[(size_t)b * nblk];
    int s1 = histS[(size_t)(b + 1) * nblk];
    for (int i = s0 + t; i < s1; i += 256)
        atomicAdd(&h[ebuf[i] >> 20], 1);
    __syncthreads();
    int v0 = h[2 * t], v1 = h[2 * t + 1];
    int ps = v0 + v1;
    int lane = t & 63, wid = t >> 6;
    int x = ps;
#pragma unroll
    for (int off = 1; off < 64; off <<= 1) {
        int y = __shfl_up(x, off, 64);
        if (lane >= off) x += y;
    }
    if (lane == 63) wq[wid] = x;
    __syncthreads();
    if (t == 0) {
        int a = 0;
#pragma unroll
        for (int w = 0; w < 4; ++w) { int tmp = wq[w]; wq[w] = a; a += tmp; }
    }
    __syncthreads();
    int excl = wq[wid] + x - ps;
    pre[2 * t]     = excl;
    pre[2 * t + 1] = excl + v0;
    __syncthreads();
    for (int i = t; i < nloc; i += 256) ip_all[d0 + i] = s0 + pre[i];
    if (d0 + nloc == NALL && t == 0) ip_all[NALL] = E_all;
    for (int i = t; i < (1 << ABITS); i += 256) h[i] = s0 + pre[i];
    __syncthreads();
    for (int i = s0 + t; i < s1; i += 256) {
        unsigned e = ebuf[i];
        int dl = (int)(e >> 20);
        int src = (int)(e & 0xFFFFFu);
        int p = atomicAdd(&h[dl], 1);
        int d = d0 + dl;
        float ssv, sdv;
        if (d < NB)           { ssv = ss_bb[src]; sdv = sd_bb[d]; }
        else if (d < NB + NP) { ssv = ss_pp[src]; sdv = sd_pp[d - NB]; }
        else                  { ssv = ss_bp[src]; sdv = sd_bp[d - NB - NP]; }
        sidx[p] = src;
        wedge[p] = __expf(lrelu2(ssv + sdv));
    }
}

// ---- gather bodies: streamed w[] (no exp / SS in the loop) ----------------
static __device__ __forceinline__ void gather1_body(
    int bid, const int* __restrict__ ip, const int* __restrict__ si,
    const float* __restrict__ w,
    const float* __restrict__ SS, const float* __restrict__ SD,
    const bf16* __restrict__ HS, const void* __restrict__ bias,
    bf16* __restrict__ OUT, int M, int bf)
{
    int lane = threadIdx.x & 63;
    int half = lane >> 5, hl = lane & 31;
    int d = bid * 4 + (threadIdx.x >> 6);
    if (d >= M) return;
    const u32* H32 = (const u32*)HS;
    float ax = 0.f, ay = 0.f, den = 0.f;
    if (half == 0) {
        float ex = __expf(lrelu2(SS[d] + SD[d]));
        u32 h = H32[(size_t)d * 32 + hl];
        ax = lo16(h) * ex; ay = hi16(h) * ex; den = ex;
    }
    int j1 = ip[d + 1];
    int j = ip[d] + half;
    for (; j + 2 < j1; j += 4) {
        int s0 = si[j], s1 = si[j + 2];
        float e0 = w[j], e1 = w[j + 2];
        u32 h0 = H32[(size_t)s0 * 32 + hl];
        u32 h1 = H32[(size_t)s1 * 32 + hl];
        ax += lo16(h0) * e0 + lo16(h1) * e1;
        ay += hi16(h0) * e0 + hi16(h1) * e1;
        den += e0 + e1;
    }
    if (j < j1) {
        int s0 = si[j];
        float e0 = w[j];
        u32 h0 = H32[(size_t)s0 * 32 + hl];
        ax += lo16(h0) * e0; ay += hi16(h0) * e0; den += e0;
    }
    ax += __shfl_xor(ax, 32); ay += __shfl_xor(ay, 32); den += __shfl_xor(den, 32);
    if (half == 0) {
        float vx = ax / den + ldf(bias, 2 * hl, bf);
        float vy = ay / den + ldf(bias, 2 * hl + 1, bf);
        vx = vx > 0.f ? vx : 0.01f * vx;
        vy = vy > 0.f ? vy : 0.01f * vy;
        ((u32*)OUT)[(size_t)d * 32 + hl] = pack2(vx, vy);
    }
}

static __device__ __forceinline__ void gather2_body(
    int bid, const int* __restrict__ ip1, const int* __restrict__ si,
    const float* __restrict__ w,
    const float* __restrict__ SS1, const float* __restrict__ SD1,
    const bf16* __restrict__ HS1,
    const int* __restrict__ ip2, const bf16* __restrict__ HS2,
    const void* __restrict__ b1, const void* __restrict__ b2,
    bf16* __restrict__ OUT, int M, int bf)
{
    int lane = threadIdx.x & 63;
    int half = lane >> 5, hl = lane & 31;
    int d = bid * 4 + (threadIdx.x >> 6);
    if (d >= M) return;
    const u32* H1 = (const u32*)HS1;
    const u32* H2 = (const u32*)HS2;
    float a1x = 0.f, a1y = 0.f, den1 = 0.f;
    if (half == 0) {
        float ex = __expf(lrelu2(SS1[d] + SD1[d]));
        u32 h = H1[(size_t)d * 32 + hl];
        a1x = lo16(h) * ex; a1y = hi16(h) * ex; den1 = ex;
    }
    int j1 = ip1[d + 1];
    int j = ip1[d] + half;
    for (; j + 2 < j1; j += 4) {
        int s0 = si[j], s1 = si[j + 2];
        float e0 = w[j], e1 = w[j + 2];
        u32 h0 = H1[(size_t)s0 * 32 + hl];
        u32 h1 = H1[(size_t)s1 * 32 + hl];
        a1x += lo16(h0) * e0 + lo16(h1) * e1;
        a1y += hi16(h0) * e0 + hi16(h1) * e1;
        den1 += e0 + e1;
    }
    if (j < j1) {
        int s0 = si[j];
        float e0 = w[j];
        u32 h0 = H1[(size_t)s0 * 32 + hl];
        a1x += lo16(h0) * e0; a1y += hi16(h0) * e0; den1 += e0;
    }
    float a2x = 0.f, a2y = 0.f, den2 = 0.f;
    j1 = ip2[d + 1];
    j = ip2[d] + half;
    for (; j + 2 < j1; j += 4) {
        int s0 = si[j], s1 = si[j + 2];
        float e0 = w[j], e1 = w[j + 2];
        u32 h0 = H2[(size_t)s0 * 32 + hl];
        u32 h1 = H2[(size_t)s1 * 32 + hl];
        a2x += lo16(h0) * e0 + lo16(h1) * e1;
        a2y += hi16(h0) * e0 + hi16(h1) * e1;
        den2 += e0 + e1;
    }
    if (j < j1) {
        int s0 = si[j];
        float e0 = w[j];
        u32 h0 = H2[(size_t)s0 * 32 + hl];
        a2x += lo16(h0) * e0; a2y += hi16(h0) * e0; den2 += e0;
    }
    a1x += __shfl_xor(a1x, 32); a1y += __shfl_xor(a1y, 32); den1 += __shfl_xor(den1, 32);
    a2x += __shfl_xor(a2x, 32); a2y += __shfl_xor(a2y, 32); den2 += __shfl_xor(den2, 32);
    if (half == 0) {
        float inv2 = den2 > 0.f ? 1.f / den2 : 0.f;
        float vx = a1x / den1 + a2x * inv2 + ldf(b1, 2 * hl, bf) + ldf(b2, 2 * hl, bf);
        float vy = a1y / den1 + a2y * inv2 + ldf(b1, 2 * hl + 1, bf) + ldf(b2, 2 * hl + 1, bf);
        vx = vx > 0.f ? vx : 0.01f * vx;
        vy = vy > 0.f ? vy : 0.01f * vy;
        ((u32*)OUT)[(size_t)d * 32 + hl] = pack2(vx, vy);
    }
}

// merged conv1 gathers
__global__ __launch_bounds__(256) void k_gather12(
    const int* __restrict__ ip_bb, const int* __restrict__ si,
    const float* __restrict__ wedge,
    const float* __restrict__ ss_bb, const float* __restrict__ sd_bb,
    const bf16* __restrict__ hs_bb, const void* __restrict__ b_bb1,
    bf16* __restrict__ hb2, int NB,
    const int* __restrict__ ip_pp, const int* __restrict__ ip_bp,
    const float* __restrict__ ss_pp, const float* __restrict__ sd_pp,
    const bf16* __restrict__ hs_pp, const bf16* __restrict__ hs_bp,
    const void* __restrict__ b_pp1, const void* __restrict__ b_bp1,
    bf16* __restrict__ hp2, int NP,
    const int* __restrict__ flag)
{
    const int bf = *flag;
    int nbb = (NB + 3) >> 2;
    if ((int)blockIdx.x < nbb)
        gather1_body(blockIdx.x, ip_bb, si, wedge, ss_bb, sd_bb, hs_bb, b_bb1, hb2, NB, bf);
    else
        gather2_body(blockIdx.x - nbb, ip_pp, si, wedge, ss_pp, sd_pp, hs_pp,
                     ip_bp, hs_bp, b_pp1, b_bp1, hp2, NP, bf);
}

// merged conv2 projections: hp2 dual32 + hb2 single32
__global__ __launch_bounds__(256) void k_proj2_all(
    const bf16* __restrict__ hp2,
    const void* W_pp2, const void* Wd_bp2,
    const void* as_pp2, const void* ad_pp2, const void* as_bp2, const void* ad_bp2,
    bf16* hs2_pp, float* ss2_pp, float* sd2_pp, float* junkNP, float* sd2_bp, int MP,
    const bf16* __restrict__ hb2,
    const void* Ws_bp2, bf16* hs2_bp, float* ss2_bp, float* junkNB, int MB,
    const int* __restrict__ flag)
{
    const int bf = *flag;
    __shared__ short WT[64 * 72];
    int npb = (MP + 63) >> 6;
    if ((int)blockIdx.x < npb)
        dual_body<32, 32, true, false>(WT, blockIdx.x, hp2, W_pp2, Wd_bp2,
            as_pp2, ad_pp2, as_bp2, ad_bp2, hs2_pp, nullptr,
            ss2_pp, sd2_pp, junkNP, sd2_bp, MP, bf);
    else
        proj_body<32, true>(WT, blockIdx.x - npb, hb2, Ws_bp2,
            as_bp2, ad_bp2, hs2_bp, ss2_bp, junkNB, MB, bf);
}

// ---- conv2 gather (C=32) + output head ------------------------------------
__global__ __launch_bounds__(256) void k_gather_out(
    const int* __restrict__ ip1, const int* __restrict__ si,
    const float* __restrict__ SS1, const float* __restrict__ SD1,
    const bf16* __restrict__ HS1,
    const int* __restrict__ ip2,
    const float* __restrict__ SS2, const float* __restrict__ SD2,
    const bf16* __restrict__ HS2,
    const void* __restrict__ b1, const void* __restrict__ b2,
    const void* __restrict__ Wout, const void* __restrict__ bout,
    void* __restrict__ OUT, int M, const int* __restrict__ flag)
{
    const int bf = *flag;
    int lane = threadIdx.x & 63;
    int q = lane >> 4, hl = lane & 15;
    int d = blockIdx.x * 4 + (threadIdx.x >> 6);
    if (d >= M) return;
    const u32* H1 = (const u32*)HS1;
    const u32* H2 = (const u32*)HS2;
    float sdd = SD1[d];
    float a1x = 0.f, a1y = 0.f, den1 = 0.f;
    if (q == 0) {
        float ex = __expf(lrelu2(SS1[d] + sdd));
        u32 h = H1[(size_t)d * 16 + hl];
        a1x = lo16(h) * ex; a1y = hi16(h) * ex; den1 = ex;
    }
    int j1 = ip1[d + 1];
    for (int j = ip1[d] + q; j < j1; j += 4) {
        int s0 = si[j];
        u32 h0 = H1[(size_t)s0 * 16 + hl];
        float e0 = __expf(lrelu2(SS1[s0] + sdd));
        a1x += lo16(h0) * e0; a1y += hi16(h0) * e0; den1 += e0;
    }
    float sdd2 = SD2[d];
    float a2x = 0.f, a2y = 0.f, den2 = 0.f;
    j1 = ip2[d + 1];
    for (int j = ip2[d] + q; j < j1; j += 4) {
        int s0 = si[j];
        u32 h0 = H2[(size_t)s0 * 16 + hl];
        float e0 = __expf(lrelu2(SS2[s0] + sdd2));
        a2x += lo16(h0) * e0; a2y += hi16(h0) * e0; den2 += e0;
    }
    a1x += __shfl_xor(a1x, 16); a1y += __shfl_xor(a1y, 16); den1 += __shfl_xor(den1, 16);
    a2x += __shfl_xor(a2x, 16); a2y += __shfl_xor(a2y, 16); den2 += __shfl_xor(den2, 16);
    a1x += __shfl_xor(a1x, 32); a1y += __shfl_xor(a1y, 32); den1 += __shfl_xor(den1, 32);
    a2x += __shfl_xor(a2x, 32); a2y += __shfl_xor(a2y, 32); den2 += __shfl_xor(den2, 32);
    float inv2 = den2 > 0.f ? 1.f / den2 : 0.f;
    float vx = a1x / den1 + a2x * inv2 + ldf(b1, 2 * hl, bf) + ldf(b2, 2 * hl, bf);
    float vy = a1y / den1 + a2y * inv2 + ldf(b1, 2 * hl + 1, bf) + ldf(b2, 2 * hl + 1, bf);
    vx = vx > 0.f ? vx : 0.01f * vx;
    vy = vy > 0.f ? vy : 0.01f * vy;
    float t = vx * ldf(Wout, 2 * hl, bf) + vy * ldf(Wout, 2 * hl + 1, bf);
#pragma unroll
    for (int off = 1; off < 16; off <<= 1) t += __shfl_xor(t, off);
    if (lane == 0) {
        float r = t + ldf(bout, 0, bf);
        if (bf) ((bf16*)OUT)[d] = __float2bfloat16(r);
        else    ((float*)OUT)[d] = r;
    }
}

// ---------------------------------------------------------------------------
extern "C" void kernel_launch(void* const* d_in, const int* in_sizes, int n_in,
                              void* d_out, int out_size, void* d_ws, size_t ws_size,
                              hipStream_t stream)
{
    const void* x_b = d_in[0];
    const void* x_p = d_in[1];
    const int* ei_bb = (const int*)d_in[2];
    const int* ei_pp = (const int*)d_in[3];
    const int* bp_s  = (const int*)d_in[4];
    const int* bp_d  = (const int*)d_in[5];
    const void *W_in_b = d_in[6],  *b_in_b = d_in[7];
    const void *W_in_p = d_in[8],  *b_in_p = d_in[9];
    const void *W_bb1 = d_in[10], *as_bb1 = d_in[11], *ad_bb1 = d_in[12], *b_bb1 = d_in[13];
    const void *W_pp1 = d_in[14], *as_pp1 = d_in[15], *ad_pp1 = d_in[16], *b_pp1 = d_in[17];
    const void *Ws_bp1 = d_in[18], *Wd_bp1 = d_in[19], *as_bp1 = d_in[20], *ad_bp1 = d_in[21], *b_bp1 = d_in[22];
    // d_in[23..26] = conv2 b->b params: dead code in reference
    const void *W_pp2 = d_in[27], *as_pp2 = d_in[28], *ad_pp2 = d_in[29], *b_pp2 = d_in[30];
    const void *Ws_bp2 = d_in[31], *Wd_bp2 = d_in[32], *as_bp2 = d_in[33], *ad_bp2 = d_in[34], *b_bp2 = d_in[35];
    const void *W_out = d_in[36], *b_out = d_in[37];

    const int NB   = in_sizes[0] / 32;
    const int NP   = in_sizes[1] / 34;
    const int E_bb = in_sizes[2] / 2;
    const int E_pp = in_sizes[3] / 2;
    const int E_bp = in_sizes[4];
    const int E_all = E_bb + E_pp + E_bp;
    const int NALL  = NB + 2 * NP;
    const int* bb_s = ei_bb;  const int* bb_d = ei_bb + E_bb;
    const int* pp_s = ei_pp;  const int* pp_d = ei_pp + E_pp;
    (void)ws_size; (void)n_in; (void)out_size;

    const int nbkt  = (NALL + (1 << ABITS) - 1) >> ABITS;
    const int nblk  = (E_all + CHUNKE - 1) / CHUNKE;
    const int nh    = nbkt * nblk;

    char* base = (char*)d_ws;
    size_t o = 0;
    auto alloc = [&](size_t bytes) { char* p = base + o; o += (bytes + 255) & ~(size_t)255; return p; };

    // --- small persistent ---
    int* flag  = (int*)alloc(256);
    int* bsum  = (int*)alloc(1024 * 4);
    int* histM = (int*)alloc((size_t)nh * 4);
    int* histS = (int*)alloc((size_t)(nh + 1) * 4);
    int* ip_all = (int*)alloc((size_t)(NALL + 1) * 4);
    unsigned* ebuf = (unsigned*)alloc((size_t)E_all * 4);
    int* si_all = (int*)alloc((size_t)E_all * 4);
    float* wedge = (float*)alloc((size_t)E_all * 4);
    float* ss_bb = (float*)alloc((size_t)NB * 4);
    float* sd_bb = (float*)alloc((size_t)NB * 4);
    float* ss_bp = (float*)alloc((size_t)NB * 4);
    float* ss_pp = (float*)alloc((size_t)NP * 4);
    float* sd_pp = (float*)alloc((size_t)NP * 4);
    float* sd_bp = (float*)alloc((size_t)NP * 4);
    float* junkNB = (float*)alloc((size_t)NB * 4);   // separate: ebuf live during E
    float* junkNP = (float*)alloc((size_t)NP * 4);
    float* ss2_bp = ss_bb;   // ss_bb dead after k_finalize+k_gather12
    float* ss2_pp = ss_pp;
    float* sd2_pp = sd_pp;
    float* sd2_bp = sd_bp;

    // --- feature slots (liveness re-verified for merged kernels) ---
    char* S1 = alloc((size_t)NB * 64 * 2);   // hb -> hs2_bp
    char* S2 = alloc((size_t)NP * 64 * 2);   // hp -> hp2
    char* S3 = alloc((size_t)NB * 64 * 2);   // hs_bb -> hs2_pp
    char* S4 = alloc((size_t)NB * 64 * 2);   // hb2
    char* S5 = alloc((size_t)NB * 64 * 2);   // hs_bp
    char* S6 = alloc((size_t)NP * 64 * 2);   // hs_pp

    bf16* hb     = (bf16*)S1;
    bf16* hp     = (bf16*)S2;
    bf16* hs_bb  = (bf16*)S3;
    bf16* hb2    = (bf16*)S4;
    bf16* hs_bp  = (bf16*)S5;
    bf16* hs_pp  = (bf16*)S6;
    bf16* hp2    = (bf16*)S2;
    bf16* hs2_pp = (bf16*)S3;
    bf16* hs2_bp = (bf16*)S1;

    auto cdiv = [](int a, int b) { return (a + b - 1) / b; };

    const int* ip_bb = ip_all;
    const int* ip_pp = ip_all + NB;
    const int* ip_bp = ip_all + NB + NP;

    // A. bucket hist ∥ input projections (probe inline)
    k_hist_inproj<<<nblk + cdiv(NB, 64) + cdiv(NP, 64), 256, 0, stream>>>(
        bb_d, pp_d, bp_d, histM, (const unsigned*)x_b, flag,
        E_bb, E_pp, E_bp, NB, NP, nbkt, nblk,
        x_b, W_in_b, b_in_b, hb, NB, x_p, W_in_p, b_in_p, hp, NP);

    // B-D. scan histM -> histS
    int sb1 = cdiv(nh, 1024);
    k_scan1<<<sb1, 1024, 0, stream>>>(histM, histS, bsum, nh);
    k_scan2<<<1, 1024, 0, stream>>>(bsum, sb1);
    k_scan3<<<sb1, 1024, 0, stream>>>(histS, bsum, nh, E_all);

    // E. bucket scatter ∥ conv1 dual projections
    k_scatter_dual<<<nblk + cdiv(NB, 64) + cdiv(NP, 64), 256, 0, stream>>>(
        bb_s, bb_d, pp_s, pp_d, bp_s, bp_d, histS, ebuf,
        E_bb, E_pp, E_bp, NB, NP, nbkt, nblk,
        hb, W_bb1, Ws_bp1, as_bb1, ad_bb1, as_bp1, ad_bp1,
        hs_bb, hs_bp, ss_bb, sd_bb, ss_bp, junkNB, NB,
        hp, W_pp1, Wd_bp1, as_pp1, ad_pp1,
        hs_pp, ss_pp, sd_pp, junkNP, sd_bp, NP, flag);

    // F. finalize CSR + emit conv1 edge weights
    k_finalize<<<nbkt, 256, 0, stream>>>(ebuf, histS, ip_all, si_all, wedge,
                                         ss_bb, sd_bb, ss_pp, sd_pp, ss_bp, sd_bp,
                                         NB, NP, NALL, E_all, nbkt, nblk);

    // G. conv1 gathers (merged; streamed w)
    k_gather12<<<cdiv(NB, 4) + cdiv(NP, 4), 256, 0, stream>>>(
        ip_bb, si_all, wedge, ss_bb, sd_bb, hs_bb, b_bb1, hb2, NB,
        ip_pp, ip_bp, ss_pp, sd_pp, hs_pp, hs_bp,
        b_pp1, b_bp1, hp2, NP, flag);

    // H. conv2 projections (merged)
    k_proj2_all<<<cdiv(NP, 64) + cdiv(NB, 64), 256, 0, stream>>>(
        hp2, W_pp2, Wd_bp2, as_pp2, ad_pp2, as_bp2, ad_bp2,
        hs2_pp, ss2_pp, sd2_pp, junkNP, sd2_bp, NP,
        hb2, Ws_bp2, hs2_bp, ss2_bp, junkNB, NB, flag);

    // I. conv2 gather + output head
    k_gather_out<<<cdiv(NP, 4), 256, 0, stream>>>(
        ip_pp, si_all, ss2_pp, sd2_pp, hs2_pp,
        ip_bp, ss2_bp, sd2_bp, hs2_bp,
        b_pp2, b_bp2, W_out, b_out, d_out, NP, flag);
}

// Round 11
// 394.366 us; speedup vs baseline: 1.1007x; 1.0058x over previous
//
#include <hip/hip_runtime.h>
#include <hip/hip_bf16.h>
#include <cstdint>
#include <cstddef>

// ---------------------------------------------------------------------------
// HeteroGNN (2-layer hetero GAT) on MI355X, gfx950.  Round 11.
//  - Conv1 edge payload packed: finalize writes int2{src, bits(w)} -> gathers
//    do ONE 8B load per edge (was 2 x 4B from separate streams).
//  - Deeper gather unroll: 4 edges/half (C=64) and 2 edges/quad (C=32) ->
//    8 random row-fetches in flight per wave (was 4).  Discriminates
//    MLP-bound vs L3-random-BW-bound (~1.1 TB/s L2-miss rate seen r8-r10).
//  - Everything else retained from round 10: CSR ∥ projection grid-split
//    merges, LDS-bucket CSR with fused finalize, MFMA projections,
//    softmax max-drop, dead conv2-b->b skip.
// ---------------------------------------------------------------------------

typedef __attribute__((ext_vector_type(8))) short short8;   // 8 bf16 (4 VGPR)
typedef __attribute__((ext_vector_type(4))) float f32x4;    // MFMA acc
typedef unsigned int u32;
typedef __hip_bfloat16 bf16;

#define ABITS 9             // bucket = concat_dst >> ABITS  (512 dsts/bucket)
#define CHUNKE 8192         // edges per block in bucket passes

static __device__ __forceinline__ float b2f(bf16 v) { return __bfloat162float(v); }

static __device__ __forceinline__ float ldf(const void* p, int i, int bf) {
    return bf ? __bfloat162float(((const bf16*)p)[i]) : ((const float*)p)[i];
}

static __device__ __forceinline__ short f2bs(float f) {
    bf16 h = __float2bfloat16(f);
    return *reinterpret_cast<short*>(&h);
}
static __device__ __forceinline__ float bs2f(short s) {
    bf16 h = *reinterpret_cast<bf16*>(&s);
    return __bfloat162float(h);
}
static __device__ __forceinline__ float lo16(u32 u) { return bs2f((short)(u & 0xffffu)); }
static __device__ __forceinline__ float hi16(u32 u) { return bs2f((short)(u >> 16)); }
static __device__ __forceinline__ u32 pack2(float x, float y) {
    return (u32)(unsigned short)f2bs(x) | ((u32)(unsigned short)f2bs(y) << 16);
}
static __device__ __forceinline__ float sel4(const float* a, int i) {
    return i == 0 ? a[0] : i == 1 ? a[1] : i == 2 ? a[2] : a[3];
}
static __device__ __forceinline__ float lrelu2(float x) { return x > 0.f ? x : 0.2f * x; }

// per-block inline dtype probe (4 KB of x_b, L2-hot after first block)
static __device__ __forceinline__ int probe_bf(const unsigned* __restrict__ w, int* cnt) {
    if (threadIdx.x == 0) *cnt = 0;
    __syncthreads();
    int c = 0;
#pragma unroll
    for (int j = 0; j < 4; ++j) {
        unsigned u = w[threadIdx.x * 4 + j];
        unsigned e = (u >> 7) & 0xffu;
        c += (e >= 100u && e <= 145u) ? 1 : 0;
    }
    atomicAdd(cnt, c);
    __syncthreads();
    int r = (*cnt > 614) ? 1 : 0;
    __syncthreads();
    return r;
}

// ---- MFMA input projection body -------------------------------------------
template <int CIN>
static __device__ __forceinline__ void in_proj_body(
    short* WT, float* bl, int bid,
    const void* __restrict__ X, const void* __restrict__ W, const void* __restrict__ B,
    bf16* __restrict__ Y, int M, int bf)
{
    constexpr int KP = 40;
    for (int i = threadIdx.x; i < 64 * CIN; i += 256) {
        int n = i / CIN, k = i - n * CIN;
        WT[n * KP + k] = f2bs(ldf(W, k * 64 + n, bf));
    }
    if (threadIdx.x < 64) bl[threadIdx.x] = ldf(B, threadIdx.x, bf);
    __syncthreads();

    int lane = threadIdx.x & 63;
    int wv   = threadIdx.x >> 6;
    int m = lane & 15, quad = lane >> 4;
    int row0 = (bid * 4 + wv) * 16;
    if (row0 >= M) return;

    int arow = row0 + m; if (arow >= M) arow = M - 1;
    short8 a;
#pragma unroll
    for (int j = 0; j < 8; ++j)
        a[j] = f2bs(ldf(X, arow * CIN + quad * 8 + j, bf));

    f32x4 acc[4] = {};
#pragma unroll
    for (int tt = 0; tt < 4; ++tt) {
        short8 bfr = *(const short8*)&WT[((lane & 15) + 16 * tt) * KP + quad * 8];
        acc[tt] = __builtin_amdgcn_mfma_f32_16x16x32_bf16(a, bfr, acc[tt], 0, 0, 0);
    }

    if (CIN == 34) {
        float x32[4], x33[4];
#pragma unroll
        for (int r = 0; r < 4; ++r) {
            int row = row0 + quad * 4 + r; if (row >= M) row = M - 1;
            x32[r] = ldf(X, row * CIN + 32, bf);
            x33[r] = ldf(X, row * CIN + 33, bf);
        }
#pragma unroll
        for (int tt = 0; tt < 4; ++tt) {
            int col = (lane & 15) + 16 * tt;
            float w32 = bs2f(WT[col * KP + 32]);
            float w33 = bs2f(WT[col * KP + 33]);
#pragma unroll
            for (int r = 0; r < 4; ++r)
                acc[tt][r] += x32[r] * w32 + x33[r] * w33;
        }
    }

#pragma unroll
    for (int tt = 0; tt < 4; ++tt) {
        int col = (lane & 15) + 16 * tt;
        float bb = bl[col];
#pragma unroll
        for (int r = 0; r < 4; ++r) {
            int row = row0 + quad * 4 + r;
            if (row < M) {
                float v = acc[tt][r] + bb;
                v = v > 0.f ? v : 0.01f * v;
                Y[(size_t)row * 64 + col] = __float2bfloat16(v);
            }
        }
    }
}

// ---- A: bucket hist ∥ input projections ----------------------------------
__global__ __launch_bounds__(256) void k_hist_inproj(
    const int* __restrict__ bb_d, const int* __restrict__ pp_d,
    const int* __restrict__ bp_d, int* __restrict__ histM,
    const unsigned* __restrict__ probe_w, int* __restrict__ flag,
    int E_bb, int E_pp, int E_bp, int NB, int NP, int nbkt, int nblk,
    const void* __restrict__ Xb, const void* __restrict__ Wb, const void* __restrict__ Bb,
    bf16* __restrict__ Yb, int MB,
    const void* __restrict__ Xp, const void* __restrict__ Wp, const void* __restrict__ Bp,
    bf16* __restrict__ Yp, int MP)
{
    __shared__ short WT[64 * 40];
    __shared__ float bl[64];
    __shared__ int aux[1 << ABITS];
    if ((int)blockIdx.x < nblk) {
        if (blockIdx.x == 0) {
            int b = probe_bf(probe_w, &aux[0]);
            if (threadIdx.x == 0) *flag = b;
        }
        for (int i = threadIdx.x; i < nbkt; i += 256) aux[i] = 0;
        __syncthreads();
        int E_all = E_bb + E_pp + E_bp;
        int base = blockIdx.x * CHUNKE;
        int end = base + CHUNKE < E_all ? base + CHUNKE : E_all;
        for (int i = base + threadIdx.x; i < end; i += 256) {
            int d;
            if (i < E_bb) d = bb_d[i];
            else if (i < E_bb + E_pp) d = NB + pp_d[i - E_bb];
            else d = NB + NP + bp_d[i - E_bb - E_pp];
            atomicAdd(&aux[d >> ABITS], 1);
        }
        __syncthreads();
        for (int i = threadIdx.x; i < nbkt; i += 256)
            histM[(size_t)i * nblk + blockIdx.x] = aux[i];
    } else {
        int bfv = probe_bf(probe_w, &aux[0]);
        int bid = blockIdx.x - nblk;
        int nbb = (MB + 63) >> 6;
        if (bid < nbb) in_proj_body<32>(WT, bl, bid, Xb, Wb, Bb, Yb, MB, bfv);
        else           in_proj_body<34>(WT, bl, bid - nbb, Xp, Wp, Bp, Yp, MP, bfv);
    }
}

// ---- scans over histM -----------------------------------------------------
__global__ __launch_bounds__(1024) void k_scan1(const int* __restrict__ deg,
                                                int* __restrict__ out,
                                                int* __restrict__ bsum, int n)
{
    __shared__ int wsum[16];
    int gid = blockIdx.x * 1024 + threadIdx.x;
    int lane = threadIdx.x & 63, wid = threadIdx.x >> 6;
    int v = (gid < n) ? deg[gid] : 0;
    int x = v;
#pragma unroll
    for (int off = 1; off < 64; off <<= 1) {
        int y = __shfl_up(x, off, 64);
        if (lane >= off) x += y;
    }
    if (lane == 63) wsum[wid] = x;
    __syncthreads();
    if (wid == 0 && lane < 16) {
        int w0 = wsum[lane];
#pragma unroll
        for (int off = 1; off < 16; off <<= 1) {
            int y = __shfl_up(w0, off, 16);
            if (lane >= off) w0 += y;
        }
        wsum[lane] = w0;
    }
    __syncthreads();
    int base = (wid > 0) ? wsum[wid - 1] : 0;
    int incl = base + x;
    if (gid < n) out[gid] = incl - v;
    if (threadIdx.x == 1023) bsum[blockIdx.x] = incl;
}

__global__ __launch_bounds__(1024) void k_scan2(int* __restrict__ bsum, int nb)
{
    __shared__ int wsum[16];
    int lane = threadIdx.x & 63, wid = threadIdx.x >> 6;
    int v = (threadIdx.x < nb) ? bsum[threadIdx.x] : 0;
    int x = v;
#pragma unroll
    for (int off = 1; off < 64; off <<= 1) {
        int y = __shfl_up(x, off, 64);
        if (lane >= off) x += y;
    }
    if (lane == 63) wsum[wid] = x;
    __syncthreads();
    if (wid == 0 && lane < 16) {
        int w0 = wsum[lane];
#pragma unroll
        for (int off = 1; off < 16; off <<= 1) {
            int y = __shfl_up(w0, off, 16);
            if (lane >= off) w0 += y;
        }
        wsum[lane] = w0;
    }
    __syncthreads();
    int base = (wid > 0) ? wsum[wid - 1] : 0;
    if (threadIdx.x < nb) bsum[threadIdx.x] = base + x - v;
}

__global__ __launch_bounds__(1024) void k_scan3(int* __restrict__ indptr,
                                                const int* __restrict__ bsum,
                                                int n, int E)
{
    int gid = blockIdx.x * 1024 + threadIdx.x;
    if (gid < n) indptr[gid] += bsum[blockIdx.x];
    if (gid == 0) indptr[n] = E;
}

// ---- MFMA dual GAT projection body ----------------------------------------
template <int N1, int N2, bool S1F, bool S2F>
static __device__ __forceinline__ void dual_body(
    short* WT, int bid, const bf16* __restrict__ H,
    const void* __restrict__ W1, const void* __restrict__ W2,
    const void* __restrict__ as1, const void* __restrict__ ad1,
    const void* __restrict__ as2, const void* __restrict__ ad2,
    bf16* __restrict__ HS1, bf16* __restrict__ HS2,
    float* __restrict__ SS1, float* __restrict__ SD1,
    float* __restrict__ SS2, float* __restrict__ SD2,
    int M, int bf)
{
    constexpr int KP = 72;
    constexpr int T1 = N1 / 16, T2 = N2 / 16, T = T1 + T2;
    for (int i = threadIdx.x; i < N1 * 64; i += 256) {
        int n = i >> 6, k = i & 63;
        WT[n * KP + k] = f2bs(ldf(W1, k * N1 + n, bf));
    }
    for (int i = threadIdx.x; i < N2 * 64; i += 256) {
        int n = i >> 6, k = i & 63;
        WT[(N1 + n) * KP + k] = f2bs(ldf(W2, k * N2 + n, bf));
    }
    __syncthreads();

    int lane = threadIdx.x & 63;
    int wv   = threadIdx.x >> 6;
    int m = lane & 15, quad = lane >> 4;
    int row0 = (bid * 4 + wv) * 16;
    if (row0 >= M) return;

    const short* Hs = (const short*)H;
    int arow = row0 + m; if (arow >= M) arow = M - 1;

    f32x4 acc[T] = {};
#pragma unroll
    for (int ks = 0; ks < 2; ++ks) {
        short8 a = *(const short8*)&Hs[(size_t)arow * 64 + ks * 32 + quad * 8];
#pragma unroll
        for (int tt = 0; tt < T; ++tt) {
            short8 bfr = *(const short8*)&WT[((lane & 15) + 16 * tt) * KP + ks * 32 + quad * 8];
            acc[tt] = __builtin_amdgcn_mfma_f32_16x16x32_bf16(a, bfr, acc[tt], 0, 0, 0);
        }
    }

    float vs1[4] = {}, vd1[4] = {}, vs2[4] = {}, vd2[4] = {};
#pragma unroll
    for (int tt = 0; tt < T1; ++tt) {
        int col = (lane & 15) + 16 * tt;
        float av = ldf(as1, col, bf), dv = ldf(ad1, col, bf);
#pragma unroll
        for (int r = 0; r < 4; ++r) {
            vs1[r] += acc[tt][r] * av;
            vd1[r] += acc[tt][r] * dv;
        }
    }
#pragma unroll
    for (int tt = 0; tt < T2; ++tt) {
        int col = (lane & 15) + 16 * tt;
        float av = ldf(as2, col, bf), dv = ldf(ad2, col, bf);
#pragma unroll
        for (int r = 0; r < 4; ++r) {
            vs2[r] += acc[T1 + tt][r] * av;
            vd2[r] += acc[T1 + tt][r] * dv;
        }
    }
#pragma unroll
    for (int off = 1; off < 16; off <<= 1)
#pragma unroll
        for (int r = 0; r < 4; ++r) {
            vs1[r] += __shfl_xor(vs1[r], off);
            vd1[r] += __shfl_xor(vd1[r], off);
            vs2[r] += __shfl_xor(vs2[r], off);
            vd2[r] += __shfl_xor(vd2[r], off);
        }
    int c = lane & 15;
    {
        int row = row0 + quad * 4 + (c & 3);
        if (row < M) {
            if (c < 4)       SS1[row] = sel4(vs1, c & 3);
            else if (c < 8)  SD1[row] = sel4(vd1, c & 3);
            else if (c < 12) SS2[row] = sel4(vs2, c & 3);
            else             SD2[row] = sel4(vd2, c & 3);
        }
    }

    if (S1F) {
#pragma unroll
        for (int tt = 0; tt < T1; ++tt) {
            int col = (lane & 15) + 16 * tt;
#pragma unroll
            for (int r = 0; r < 4; ++r) {
                int row = row0 + quad * 4 + r;
                if (row < M)
                    HS1[(size_t)row * N1 + col] = __float2bfloat16(acc[tt][r]);
            }
        }
    }
    if (S2F) {
#pragma unroll
        for (int tt = 0; tt < T2; ++tt) {
            int col = (lane & 15) + 16 * tt;
#pragma unroll
            for (int r = 0; r < 4; ++r) {
                int row = row0 + quad * 4 + r;
                if (row < M)
                    HS2[(size_t)row * N2 + col] = __float2bfloat16(acc[T1 + tt][r]);
            }
        }
    }
}

// ---- MFMA single GAT projection body --------------------------------------
template <int N, bool STORE>
static __device__ __forceinline__ void proj_body(
    short* WT, int bid, const bf16* __restrict__ H, const void* __restrict__ W,
    const void* __restrict__ a_s, const void* __restrict__ a_d,
    bf16* __restrict__ HS, float* __restrict__ SS, float* __restrict__ SD,
    int M, int bf)
{
    constexpr int KP = 72;
    constexpr int T = N / 16;
    for (int i = threadIdx.x; i < N * 64; i += 256) {
        int n = i >> 6, k = i & 63;
        WT[n * KP + k] = f2bs(ldf(W, k * N + n, bf));
    }
    __syncthreads();

    int lane = threadIdx.x & 63;
    int wv   = threadIdx.x >> 6;
    int m = lane & 15, quad = lane >> 4;
    int row0 = (bid * 4 + wv) * 16;
    if (row0 >= M) return;

    const short* Hs = (const short*)H;
    int arow = row0 + m; if (arow >= M) arow = M - 1;

    f32x4 acc[T] = {};
#pragma unroll
    for (int ks = 0; ks < 2; ++ks) {
        short8 a = *(const short8*)&Hs[(size_t)arow * 64 + ks * 32 + quad * 8];
#pragma unroll
        for (int tt = 0; tt < T; ++tt) {
            short8 bfr = *(const short8*)&WT[((lane & 15) + 16 * tt) * KP + ks * 32 + quad * 8];
            acc[tt] = __builtin_amdgcn_mfma_f32_16x16x32_bf16(a, bfr, acc[tt], 0, 0, 0);
        }
    }

    float asv[T], adv[T];
#pragma unroll
    for (int tt = 0; tt < T; ++tt) {
        int col = (lane & 15) + 16 * tt;
        asv[tt] = ldf(a_s, col, bf);
        adv[tt] = ldf(a_d, col, bf);
    }
    float vs[4] = {}, vd[4] = {};
#pragma unroll
    for (int tt = 0; tt < T; ++tt)
#pragma unroll
        for (int r = 0; r < 4; ++r) {
            vs[r] += acc[tt][r] * asv[tt];
            vd[r] += acc[tt][r] * adv[tt];
        }
#pragma unroll
    for (int off = 1; off < 16; off <<= 1)
#pragma unroll
        for (int r = 0; r < 4; ++r) {
            vs[r] += __shfl_xor(vs[r], off);
            vd[r] += __shfl_xor(vd[r], off);
        }
    int c = lane & 15;
    if (c < 8) {
        int row = row0 + quad * 4 + (c & 3);
        if (row < M) {
            if (c < 4) SS[row] = sel4(vs, c & 3);
            else       SD[row] = sel4(vd, c & 3);
        }
    }

    if (STORE) {
#pragma unroll
        for (int tt = 0; tt < T; ++tt) {
            int col = (lane & 15) + 16 * tt;
#pragma unroll
            for (int r = 0; r < 4; ++r) {
                int row = row0 + quad * 4 + r;
                if (row < M)
                    HS[(size_t)row * N + col] = __float2bfloat16(acc[tt][r]);
            }
        }
    }
}

// ---- E: bucket scatter ∥ conv1 dual projections ---------------------------
__global__ __launch_bounds__(256) void k_scatter_dual(
    const int* __restrict__ bb_s, const int* __restrict__ bb_d,
    const int* __restrict__ pp_s, const int* __restrict__ pp_d,
    const int* __restrict__ bp_s, const int* __restrict__ bp_d,
    const int* __restrict__ histS, unsigned* __restrict__ ebuf,
    int E_bb, int E_pp, int E_bp, int NB, int NP, int nbkt, int nblk,
    const bf16* __restrict__ hb,
    const void* W_bb1, const void* Ws_bp1,
    const void* as_bb1, const void* ad_bb1, const void* as_bp1, const void* ad_bp1,
    bf16* hs_bb, bf16* hs_bp,
    float* ss_bb, float* sd_bb, float* ss_bp, float* junkNB, int MB,
    const bf16* __restrict__ hp,
    const void* W_pp1, const void* Wd_bp1,
    const void* as_pp1, const void* ad_pp1,
    bf16* hs_pp, float* ss_pp, float* sd_pp, float* junkNP, float* sd_bp, int MP,
    const int* __restrict__ flag)
{
    __shared__ short WT[128 * 72];
    if ((int)blockIdx.x < nblk) {
        int* cur = (int*)WT;
        for (int i = threadIdx.x; i < nbkt; i += 256)
            cur[i] = histS[(size_t)i * nblk + blockIdx.x];
        __syncthreads();
        int E_all = E_bb + E_pp + E_bp;
        int base = blockIdx.x * CHUNKE;
        int end = base + CHUNKE < E_all ? base + CHUNKE : E_all;
        for (int i = base + threadIdx.x; i < end; i += 256) {
            int s, d;
            if (i < E_bb) { s = bb_s[i]; d = bb_d[i]; }
            else if (i < E_bb + E_pp) { int j = i - E_bb; s = pp_s[j]; d = NB + pp_d[j]; }
            else { int j = i - E_bb - E_pp; s = bp_s[j]; d = NB + NP + bp_d[j]; }
            int p = atomicAdd(&cur[d >> ABITS], 1);
            ebuf[p] = ((unsigned)(d & ((1 << ABITS) - 1)) << 20) | (unsigned)s;
        }
    } else {
        const int bfv = *flag;
        int bid = blockIdx.x - nblk;
        int nbb = (MB + 63) >> 6;
        if (bid < nbb)
            dual_body<64, 64, true, true>(WT, bid, hb, W_bb1, Ws_bp1,
                as_bb1, ad_bb1, as_bp1, ad_bp1, hs_bb, hs_bp,
                ss_bb, sd_bb, ss_bp, junkNB, MB, bfv);
        else
            dual_body<64, 64, true, false>(WT, bid - nbb, hp, W_pp1, Wd_bp1,
                as_pp1, ad_pp1, as_bp1, ad_bp1, hs_pp, nullptr,
                ss_pp, sd_pp, junkNP, sd_bp, MP, bfv);
    }
}

// ---- F: finalize CSR + emit packed (src, w) edge payload ------------------
__global__ __launch_bounds__(256) void k_finalize(
    const unsigned* __restrict__ ebuf, const int* __restrict__ histS,
    int* __restrict__ ip_all, int2* __restrict__ sw,
    const float* __restrict__ ss_bb, const float* __restrict__ sd_bb,
    const float* __restrict__ ss_pp, const float* __restrict__ sd_pp,
    const float* __restrict__ ss_bp, const float* __restrict__ sd_bp,
    int NB, int NP, int NALL, int E_all, int nbkt, int nblk)
{
    __shared__ int h[1 << ABITS];
    __shared__ int pre[1 << ABITS];
    __shared__ int wq[4];
    int b = blockIdx.x;
    int d0 = b << ABITS;
    int nloc = NALL - d0 < (1 << ABITS) ? NALL - d0 : (1 << ABITS);
    int t = threadIdx.x;
    for (int i = t; i < (1 << ABITS); i += 256) h[i] = 0;
    __syncthreads();
    int s0 = histS[(size_t)b * nblk];
    int s1 = histS[(size_t)(b + 1) * nblk];
    for (int i = s0 + t; i < s1; i += 256)
        atomicAdd(&h[ebuf[i] >> 20], 1);
    __syncthreads();
    int v0 = h[2 * t], v1 = h[2 * t + 1];
    int ps = v0 + v1;
    int lane = t & 63, wid = t >> 6;
    int x = ps;
#pragma unroll
    for (int off = 1; off < 64; off <<= 1) {
        int y = __shfl_up(x, off, 64);
        if (lane >= off) x += y;
    }
    if (lane == 63) wq[wid] = x;
    __syncthreads();
    if (t == 0) {
        int a = 0;
#pragma unroll
        for (int w = 0; w < 4; ++w) { int tmp = wq[w]; wq[w] = a; a += tmp; }
    }
    __syncthreads();
    int excl = wq[wid] + x - ps;
    pre[2 * t]     = excl;
    pre[2 * t + 1] = excl + v0;
    __syncthreads();
    for (int i = t; i < nloc; i += 256) ip_all[d0 + i] = s0 + pre[i];
    if (d0 + nloc == NALL && t == 0) ip_all[NALL] = E_all;
    for (int i = t; i < (1 << ABITS); i += 256) h[i] = s0 + pre[i];
    __syncthreads();
    for (int i = s0 + t; i < s1; i += 256) {
        unsigned e = ebuf[i];
        int dl = (int)(e >> 20);
        int src = (int)(e & 0xFFFFFu);
        int p = atomicAdd(&h[dl], 1);
        int d = d0 + dl;
        float ssv, sdv;
        if (d < NB)           { ssv = ss_bb[src]; sdv = sd_bb[d]; }
        else if (d < NB + NP) { ssv = ss_pp[src]; sdv = sd_pp[d - NB]; }
        else                  { ssv = ss_bp[src]; sdv = sd_bp[d - NB - NP]; }
        int2 pk; pk.x = src; pk.y = __float_as_int(__expf(lrelu2(ssv + sdv)));
        sw[p] = pk;
    }
}

// ---- gather bodies: packed int2 payload, 4 edges/half unroll --------------
static __device__ __forceinline__ void gather1_body(
    int bid, const int* __restrict__ ip, const int2* __restrict__ sw,
    const float* __restrict__ SS, const float* __restrict__ SD,
    const bf16* __restrict__ HS, const void* __restrict__ bias,
    bf16* __restrict__ OUT, int M, int bf)
{
    int lane = threadIdx.x & 63;
    int half = lane >> 5, hl = lane & 31;
    int d = bid * 4 + (threadIdx.x >> 6);
    if (d >= M) return;
    const u32* H32 = (const u32*)HS;
    float ax = 0.f, ay = 0.f, den = 0.f;
    if (half == 0) {
        float ex = __expf(lrelu2(SS[d] + SD[d]));
        u32 h = H32[(size_t)d * 32 + hl];
        ax = lo16(h) * ex; ay = hi16(h) * ex; den = ex;
    }
    int j1 = ip[d + 1];
    int j = ip[d] + half;
    for (; j + 6 < j1; j += 8) {
        int2 p0 = sw[j], p1 = sw[j + 2], p2 = sw[j + 4], p3 = sw[j + 6];
        u32 h0 = H32[(size_t)p0.x * 32 + hl];
        u32 h1 = H32[(size_t)p1.x * 32 + hl];
        u32 h2 = H32[(size_t)p2.x * 32 + hl];
        u32 h3 = H32[(size_t)p3.x * 32 + hl];
        float e0 = __int_as_float(p0.y), e1 = __int_as_float(p1.y);
        float e2 = __int_as_float(p2.y), e3 = __int_as_float(p3.y);
        ax += lo16(h0) * e0 + lo16(h1) * e1 + lo16(h2) * e2 + lo16(h3) * e3;
        ay += hi16(h0) * e0 + hi16(h1) * e1 + hi16(h2) * e2 + hi16(h3) * e3;
        den += (e0 + e1) + (e2 + e3);
    }
    for (; j < j1; j += 2) {
        int2 p0 = sw[j];
        u32 h0 = H32[(size_t)p0.x * 32 + hl];
        float e0 = __int_as_float(p0.y);
        ax += lo16(h0) * e0; ay += hi16(h0) * e0; den += e0;
    }
    ax += __shfl_xor(ax, 32); ay += __shfl_xor(ay, 32); den += __shfl_xor(den, 32);
    if (half == 0) {
        float vx = ax / den + ldf(bias, 2 * hl, bf);
        float vy = ay / den + ldf(bias, 2 * hl + 1, bf);
        vx = vx > 0.f ? vx : 0.01f * vx;
        vy = vy > 0.f ? vy : 0.01f * vy;
        ((u32*)OUT)[(size_t)d * 32 + hl] = pack2(vx, vy);
    }
}

static __device__ __forceinline__ void gather2_body(
    int bid, const int* __restrict__ ip1, const int2* __restrict__ sw,
    const float* __restrict__ SS1, const float* __restrict__ SD1,
    const bf16* __restrict__ HS1,
    const int* __restrict__ ip2, const bf16* __restrict__ HS2,
    const void* __restrict__ b1, const void* __restrict__ b2,
    bf16* __restrict__ OUT, int M, int bf)
{
    int lane = threadIdx.x & 63;
    int half = lane >> 5, hl = lane & 31;
    int d = bid * 4 + (threadIdx.x >> 6);
    if (d >= M) return;
    const u32* H1 = (const u32*)HS1;
    const u32* H2 = (const u32*)HS2;
    float a1x = 0.f, a1y = 0.f, den1 = 0.f;
    if (half == 0) {
        float ex = __expf(lrelu2(SS1[d] + SD1[d]));
        u32 h = H1[(size_t)d * 32 + hl];
        a1x = lo16(h) * ex; a1y = hi16(h) * ex; den1 = ex;
    }
    int j1 = ip1[d + 1];
    int j = ip1[d] + half;
    for (; j + 6 < j1; j += 8) {
        int2 p0 = sw[j], p1 = sw[j + 2], p2 = sw[j + 4], p3 = sw[j + 6];
        u32 h0 = H1[(size_t)p0.x * 32 + hl];
        u32 h1 = H1[(size_t)p1.x * 32 + hl];
        u32 h2 = H1[(size_t)p2.x * 32 + hl];
        u32 h3 = H1[(size_t)p3.x * 32 + hl];
        float e0 = __int_as_float(p0.y), e1 = __int_as_float(p1.y);
        float e2 = __int_as_float(p2.y), e3 = __int_as_float(p3.y);
        a1x += lo16(h0) * e0 + lo16(h1) * e1 + lo16(h2) * e2 + lo16(h3) * e3;
        a1y += hi16(h0) * e0 + hi16(h1) * e1 + hi16(h2) * e2 + hi16(h3) * e3;
        den1 += (e0 + e1) + (e2 + e3);
    }
    for (; j < j1; j += 2) {
        int2 p0 = sw[j];
        u32 h0 = H1[(size_t)p0.x * 32 + hl];
        float e0 = __int_as_float(p0.y);
        a1x += lo16(h0) * e0; a1y += hi16(h0) * e0; den1 += e0;
    }
    float a2x = 0.f, a2y = 0.f, den2 = 0.f;
    j1 = ip2[d + 1];
    j = ip2[d] + half;
    for (; j + 6 < j1; j += 8) {
        int2 p0 = sw[j], p1 = sw[j + 2], p2 = sw[j + 4], p3 = sw[j + 6];
        u32 h0 = H2[(size_t)p0.x * 32 + hl];
        u32 h1 = H2[(size_t)p1.x * 32 + hl];
        u32 h2 = H2[(size_t)p2.x * 32 + hl];
        u32 h3 = H2[(size_t)p3.x * 32 + hl];
        float e0 = __int_as_float(p0.y), e1 = __int_as_float(p1.y);
        float e2 = __int_as_float(p2.y), e3 = __int_as_float(p3.y);
        a2x += lo16(h0) * e0 + lo16(h1) * e1 + lo16(h2) * e2 + lo16(h3) * e3;
        a2y += hi16(h0) * e0 + hi16(h1) * e1 + hi16(h2) * e2 + hi16(h3) * e3;
        den2 += (e0 + e1) + (e2 + e3);
    }
    for (; j < j1; j += 2) {
        int2 p0 = sw[j];
        u32 h0 = H2[(size_t)p0.x * 32 + hl];
        float e0 = __int_as_float(p0.y);
        a2x += lo16(h0) * e0; a2y += hi16(h0) * e0; den2 += e0;
    }
    a1x += __shfl_xor(a1x, 32); a1y += __shfl_xor(a1y, 32); den1 += __shfl_xor(den1, 32);
    a2x += __shfl_xor(a2x, 32); a2y += __shfl_xor(a2y, 32); den2 += __shfl_xor(den2, 32);
    if (half == 0) {
        float inv2 = den2 > 0.f ? 1.f / den2 : 0.f;
        float vx = a1x / den1 + a2x * inv2 + ldf(b1, 2 * hl, bf) + ldf(b2, 2 * hl, bf);
        float vy = a1y / den1 + a2y * inv2 + ldf(b1, 2 * hl + 1, bf) + ldf(b2, 2 * hl + 1, bf);
        vx = vx > 0.f ? vx : 0.01f * vx;
        vy = vy > 0.f ? vy : 0.01f * vy;
        ((u32*)OUT)[(size_t)d * 32 + hl] = pack2(vx, vy);
    }
}

// merged conv1 gathers
__global__ __launch_bounds__(256) void k_gather12(
    const int* __restrict__ ip_bb, const int2* __restrict__ sw,
    const float* __restrict__ ss_bb, const float* __restrict__ sd_bb,
    const bf16* __restrict__ hs_bb, const void* __restrict__ b_bb1,
    bf16* __restrict__ hb2, int NB,
    const int* __restrict__ ip_pp, const int* __restrict__ ip_bp,
    const float* __restrict__ ss_pp, const float* __restrict__ sd_pp,
    const bf16* __restrict__ hs_pp, const bf16* __restrict__ hs_bp,
    const void* __restrict__ b_pp1, const void* __restrict__ b_bp1,
    bf16* __restrict__ hp2, int NP,
    const int* __restrict__ flag)
{
    const int bf = *flag;
    int nbb = (NB + 3) >> 2;
    if ((int)blockIdx.x < nbb)
        gather1_body(blockIdx.x, ip_bb, sw, ss_bb, sd_bb, hs_bb, b_bb1, hb2, NB, bf);
    else
        gather2_body(blockIdx.x - nbb, ip_pp, sw, ss_pp, sd_pp, hs_pp,
                     ip_bp, hs_bp, b_pp1, b_bp1, hp2, NP, bf);
}

// merged conv2 projections: hp2 dual32 + hb2 single32
__global__ __launch_bounds__(256) void k_proj2_all(
    const bf16* __restrict__ hp2,
    const void* W_pp2, const void* Wd_bp2,
    const void* as_pp2, const void* ad_pp2, const void* as_bp2, const void* ad_bp2,
    bf16* hs2_pp, float* ss2_pp, float* sd2_pp, float* junkNP, float* sd2_bp, int MP,
    const bf16* __restrict__ hb2,
    const void* Ws_bp2, bf16* hs2_bp, float* ss2_bp, float* junkNB, int MB,
    const int* __restrict__ flag)
{
    const int bf = *flag;
    __shared__ short WT[64 * 72];
    int npb = (MP + 63) >> 6;
    if ((int)blockIdx.x < npb)
        dual_body<32, 32, true, false>(WT, blockIdx.x, hp2, W_pp2, Wd_bp2,
            as_pp2, ad_pp2, as_bp2, ad_bp2, hs2_pp, nullptr,
            ss2_pp, sd2_pp, junkNP, sd2_bp, MP, bf);
    else
        proj_body<32, true>(WT, blockIdx.x - npb, hb2, Ws_bp2,
            as_bp2, ad_bp2, hs2_bp, ss2_bp, junkNB, MB, bf);
}

// ---- conv2 gather (C=32) + output head, 2 edges/quad unroll ---------------
__global__ __launch_bounds__(256) void k_gather_out(
    const int* __restrict__ ip1, const int2* __restrict__ sw,
    const float* __restrict__ SS1, const float* __restrict__ SD1,
    const bf16* __restrict__ HS1,
    const int* __restrict__ ip2,
    const float* __restrict__ SS2, const float* __restrict__ SD2,
    const bf16* __restrict__ HS2,
    const void* __restrict__ b1, const void* __restrict__ b2,
    const void* __restrict__ Wout, const void* __restrict__ bout,
    void* __restrict__ OUT, int M, const int* __restrict__ flag)
{
    const int bf = *flag;
    int lane = threadIdx.x & 63;
    int q = lane >> 4, hl = lane & 15;
    int d = blockIdx.x * 4 + (threadIdx.x >> 6);
    if (d >= M) return;
    const u32* H1 = (const u32*)HS1;
    const u32* H2 = (const u32*)HS2;
    float sdd = SD1[d];
    float a1x = 0.f, a1y = 0.f, den1 = 0.f;
    if (q == 0) {
        float ex = __expf(lrelu2(SS1[d] + sdd));
        u32 h = H1[(size_t)d * 16 + hl];
        a1x = lo16(h) * ex; a1y = hi16(h) * ex; den1 = ex;
    }
    int j1 = ip1[d + 1];
    int j = ip1[d] + q;
    for (; j + 4 < j1; j += 8) {
        int s0 = sw[j].x, s1 = sw[j + 4].x;
        u32 h0 = H1[(size_t)s0 * 16 + hl];
        u32 h1 = H1[(size_t)s1 * 16 + hl];
        float e0 = __expf(lrelu2(SS1[s0] + sdd));
        float e1 = __expf(lrelu2(SS1[s1] + sdd));
        a1x += lo16(h0) * e0 + lo16(h1) * e1;
        a1y += hi16(h0) * e0 + hi16(h1) * e1;
        den1 += e0 + e1;
    }
    if (j < j1) {
        int s0 = sw[j].x;
        u32 h0 = H1[(size_t)s0 * 16 + hl];
        float e0 = __expf(lrelu2(SS1[s0] + sdd));
        a1x += lo16(h0) * e0; a1y += hi16(h0) * e0; den1 += e0;
    }
    float sdd2 = SD2[d];
    float a2x = 0.f, a2y = 0.f, den2 = 0.f;
    j1 = ip2[d + 1];
    j = ip2[d] + q;
    for (; j + 4 < j1; j += 8) {
        int s0 = sw[j].x, s1 = sw[j + 4].x;
        u32 h0 = H2[(size_t)s0 * 16 + hl];
        u32 h1 = H2[(size_t)s1 * 16 + hl];
        float e0 = __expf(lrelu2(SS2[s0] + sdd2));
        float e1 = __expf(lrelu2(SS2[s1] + sdd2));
        a2x += lo16(h0) * e0 + lo16(h1) * e1;
        a2y += hi16(h0) * e0 + hi16(h1) * e1;
        den2 += e0 + e1;
    }
    if (j < j1) {
        int s0 = sw[j].x;
        u32 h0 = H2[(size_t)s0 * 16 + hl];
        float e0 = __expf(lrelu2(SS2[s0] + sdd2));
        a2x += lo16(h0) * e0; a2y += hi16(h0) * e0; den2 += e0;
    }
    a1x += __shfl_xor(a1x, 16); a1y += __shfl_xor(a1y, 16); den1 += __shfl_xor(den1, 16);
    a2x += __shfl_xor(a2x, 16); a2y += __shfl_xor(a2y, 16); den2 += __shfl_xor(den2, 16);
    a1x += __shfl_xor(a1x, 32); a1y += __shfl_xor(a1y, 32); den1 += __shfl_xor(den1, 32);
    a2x += __shfl_xor(a2x, 32); a2y += __shfl_xor(a2y, 32); den2 += __shfl_xor(den2, 32);
    float inv2 = den2 > 0.f ? 1.f / den2 : 0.f;
    float vx = a1x / den1 + a2x * inv2 + ldf(b1, 2 * hl, bf) + ldf(b2, 2 * hl, bf);
    float vy = a1y / den1 + a2y * inv2 + ldf(b1, 2 * hl + 1, bf) + ldf(b2, 2 * hl + 1, bf);
    vx = vx > 0.f ? vx : 0.01f * vx;
    vy = vy > 0.f ? vy : 0.01f * vy;
    float t = vx * ldf(Wout, 2 * hl, bf) + vy * ldf(Wout, 2 * hl + 1, bf);
#pragma unroll
    for (int off = 1; off < 16; off <<= 1) t += __shfl_xor(t, off);
    if (lane == 0) {
        float r = t + ldf(bout, 0, bf);
        if (bf) ((bf16*)OUT)[d] = __float2bfloat16(r);
        else    ((float*)OUT)[d] = r;
    }
}

// ---------------------------------------------------------------------------
extern "C" void kernel_launch(void* const* d_in, const int* in_sizes, int n_in,
                              void* d_out, int out_size, void* d_ws, size_t ws_size,
                              hipStream_t stream)
{
    const void* x_b = d_in[0];
    const void* x_p = d_in[1];
    const int* ei_bb = (const int*)d_in[2];
    const int* ei_pp = (const int*)d_in[3];
    const int* bp_s  = (const int*)d_in[4];
    const int* bp_d  = (const int*)d_in[5];
    const void *W_in_b = d_in[6],  *b_in_b = d_in[7];
    const void *W_in_p = d_in[8],  *b_in_p = d_in[9];
    const void *W_bb1 = d_in[10], *as_bb1 = d_in[11], *ad_bb1 = d_in[12], *b_bb1 = d_in[13];
    const void *W_pp1 = d_in[14], *as_pp1 = d_in[15], *ad_pp1 = d_in[16], *b_pp1 = d_in[17];
    const void *Ws_bp1 = d_in[18], *Wd_bp1 = d_in[19], *as_bp1 = d_in[20], *ad_bp1 = d_in[21], *b_bp1 = d_in[22];
    // d_in[23..26] = conv2 b->b params: dead code in reference
    const void *W_pp2 = d_in[27], *as_pp2 = d_in[28], *ad_pp2 = d_in[29], *b_pp2 = d_in[30];
    const void *Ws_bp2 = d_in[31], *Wd_bp2 = d_in[32], *as_bp2 = d_in[33], *ad_bp2 = d_in[34], *b_bp2 = d_in[35];
    const void *W_out = d_in[36], *b_out = d_in[37];

    const int NB   = in_sizes[0] / 32;
    const int NP   = in_sizes[1] / 34;
    const int E_bb = in_sizes[2] / 2;
    const int E_pp = in_sizes[3] / 2;
    const int E_bp = in_sizes[4];
    const int E_all = E_bb + E_pp + E_bp;
    const int NALL  = NB + 2 * NP;
    const int* bb_s = ei_bb;  const int* bb_d = ei_bb + E_bb;
    const int* pp_s = ei_pp;  const int* pp_d = ei_pp + E_pp;
    (void)ws_size; (void)n_in; (void)out_size;

    const int nbkt  = (NALL + (1 << ABITS) - 1) >> ABITS;
    const int nblk  = (E_all + CHUNKE - 1) / CHUNKE;
    const int nh    = nbkt * nblk;

    char* base = (char*)d_ws;
    size_t o = 0;
    auto alloc = [&](size_t bytes) { char* p = base + o; o += (bytes + 255) & ~(size_t)255; return p; };

    // --- small persistent ---
    int* flag  = (int*)alloc(256);
    int* bsum  = (int*)alloc(1024 * 4);
    int* histM = (int*)alloc((size_t)nh * 4);
    int* histS = (int*)alloc((size_t)(nh + 1) * 4);
    int* ip_all = (int*)alloc((size_t)(NALL + 1) * 4);
    unsigned* ebuf = (unsigned*)alloc((size_t)E_all * 4);
    int2* sw = (int2*)alloc((size_t)E_all * 8);
    float* ss_bb = (float*)alloc((size_t)NB * 4);
    float* sd_bb = (float*)alloc((size_t)NB * 4);
    float* ss_bp = (float*)alloc((size_t)NB * 4);
    float* ss_pp = (float*)alloc((size_t)NP * 4);
    float* sd_pp = (float*)alloc((size_t)NP * 4);
    float* sd_bp = (float*)alloc((size_t)NP * 4);
    float* junkNB = (float*)alloc((size_t)NB * 4);
    float* junkNP = (float*)alloc((size_t)NP * 4);
    float* ss2_bp = ss_bb;   // ss_bb dead after k_finalize+k_gather12
    float* ss2_pp = ss_pp;
    float* sd2_pp = sd_pp;
    float* sd2_bp = sd_bp;

    // --- feature slots ---
    char* S1 = alloc((size_t)NB * 64 * 2);   // hb -> hs2_bp
    char* S2 = alloc((size_t)NP * 64 * 2);   // hp -> hp2
    char* S3 = alloc((size_t)NB * 64 * 2);   // hs_bb -> hs2_pp
    char* S4 = alloc((size_t)NB * 64 * 2);   // hb2
    char* S5 = alloc((size_t)NB * 64 * 2);   // hs_bp
    char* S6 = alloc((size_t)NP * 64 * 2);   // hs_pp

    bf16* hb     = (bf16*)S1;
    bf16* hp     = (bf16*)S2;
    bf16* hs_bb  = (bf16*)S3;
    bf16* hb2    = (bf16*)S4;
    bf16* hs_bp  = (bf16*)S5;
    bf16* hs_pp  = (bf16*)S6;
    bf16* hp2    = (bf16*)S2;
    bf16* hs2_pp = (bf16*)S3;
    bf16* hs2_bp = (bf16*)S1;

    auto cdiv = [](int a, int b) { return (a + b - 1) / b; };

    const int* ip_bb = ip_all;
    const int* ip_pp = ip_all + NB;
    const int* ip_bp = ip_all + NB + NP;

    // A. bucket hist ∥ input projections (probe inline)
    k_hist_inproj<<<nblk + cdiv(NB, 64) + cdiv(NP, 64), 256, 0, stream>>>(
        bb_d, pp_d, bp_d, histM, (const unsigned*)x_b, flag,
        E_bb, E_pp, E_bp, NB, NP, nbkt, nblk,
        x_b, W_in_b, b_in_b, hb, NB, x_p, W_in_p, b_in_p, hp, NP);

    // B-D. scan histM -> histS
    int sb1 = cdiv(nh, 1024);
    k_scan1<<<sb1, 1024, 0, stream>>>(histM, histS, bsum, nh);
    k_scan2<<<1, 1024, 0, stream>>>(bsum, sb1);
    k_scan3<<<sb1, 1024, 0, stream>>>(histS, bsum, nh, E_all);

    // E. bucket scatter ∥ conv1 dual projections
    k_scatter_dual<<<nblk + cdiv(NB, 64) + cdiv(NP, 64), 256, 0, stream>>>(
        bb_s, bb_d, pp_s, pp_d, bp_s, bp_d, histS, ebuf,
        E_bb, E_pp, E_bp, NB, NP, nbkt, nblk,
        hb, W_bb1, Ws_bp1, as_bb1, ad_bb1, as_bp1, ad_bp1,
        hs_bb, hs_bp, ss_bb, sd_bb, ss_bp, junkNB, NB,
        hp, W_pp1, Wd_bp1, as_pp1, ad_pp1,
        hs_pp, ss_pp, sd_pp, junkNP, sd_bp, NP, flag);

    // F. finalize CSR + emit packed conv1 edge payload
    k_finalize<<<nbkt, 256, 0, stream>>>(ebuf, histS, ip_all, sw,
                                         ss_bb, sd_bb, ss_pp, sd_pp, ss_bp, sd_bp,
                                         NB, NP, NALL, E_all, nbkt, nblk);

    // G. conv1 gathers (merged; packed payload, 4-edge/half unroll)
    k_gather12<<<cdiv(NB, 4) + cdiv(NP, 4), 256, 0, stream>>>(
        ip_bb, sw, ss_bb, sd_bb, hs_bb, b_bb1, hb2, NB,
        ip_pp, ip_bp, ss_pp, sd_pp, hs_pp, hs_bp,
        b_pp1, b_bp1, hp2, NP, flag);

    // H. conv2 projections (merged)
    k_proj2_all<<<cdiv(NP, 64) + cdiv(NB, 64), 256, 0, stream>>>(
        hp2, W_pp2, Wd_bp2, as_pp2, ad_pp2, as_bp2, ad_bp2,
        hs2_pp, ss2_pp, sd2_pp, junkNP, sd2_bp, NP,
        hb2, Ws_bp2, hs2_bp, ss2_bp, junkNB, NB, flag);

    // I. conv2 gather + output head
    k_gather_out<<<cdiv(NP, 4), 256, 0, stream>>>(
        ip_pp, sw, ss2_pp, sd2_pp, hs2_pp,
        ip_bp, ss2_bp, sd2_bp, hs2_bp,
        b_pp2, b_bp2, W_out, b_out, d_out, NP, flag);
}